// Round 1
// baseline (15605.620 us; speedup 1.0000x reference)
//
#include <hip/hip_runtime.h>
#include <cstddef>

#define NS_ITERS 16
#define MSZ 262144  // 512*512

// ---------------- workspace offsets (in floats) ----------------
#define OFF_F4C   0ul
#define OFF_F4S   2097152ul
#define OFF_TF    4194304ul      // tf_ during style transfer; f4(dec) at the end
#define OFF_DEC   6291456ul      // 786432
#define OFF_TMAT  7077888ul      // 12*512*512
#define OFF_SMALL 10223616ul     // 131072 floats of small stuff (zeroed each launch)
#define OFF_ARENA 10354688ul     // 31457280 floats reusable arena
// total: 41,811,968 floats = ~167 MB

// SMALL sub-offsets (floats)
#define SM_CENT    0       // 8*3*512
#define SM_ASSIGN  12288   // 8*1024 ints
#define SM_MU      20480   // 24*512
#define SM_COUNTS  32768   // 24
#define SM_SVAL    32800   // 24
#define SM_SCALE   32832   // 12
#define SM_TVEC    32864   // 12*512
#define SM_STATS_S 39008   // style stats: mean[3840] then std[3840]
#define SM_STATS_D 46688   // decoded stats: same layout
#define SM_CLOSS   54368   // 1

// ---------------- kernels ----------------

__global__ __launch_bounds__(256) void zerok(float* p, int n){
  int i = blockIdx.x*256 + threadIdx.x;
  if (i < n) p[i] = 0.f;
}

// direct 3x3 SAME conv, NCHW. 32x32 spatial tile, 256 thr (2x2 px each), COT couts/block, 8-ci chunks.
template<int COT>
__global__ __launch_bounds__(256) void conv3x3(
    const float* __restrict__ in, const float* __restrict__ wgt,
    const float* __restrict__ bias, float* __restrict__ out,
    int B, int Cin, int Cout, int H, int W, int relu)
{
  __shared__ float s_in[8][34][34];
  __shared__ float s_w[COT][8][9];
  const int tid = threadIdx.x;
  const int tx = tid & 15, ty = tid >> 4;
  const int tilesW = W >> 5;
  const int h0 = (blockIdx.x / tilesW) << 5;
  const int w0 = (blockIdx.x % tilesW) << 5;
  const int co0 = blockIdx.y * COT;
  const int b = blockIdx.z;
  float acc[COT][2][2];
  #pragma unroll
  for (int o=0;o<COT;o++){acc[o][0][0]=0.f;acc[o][0][1]=0.f;acc[o][1][0]=0.f;acc[o][1][1]=0.f;}
  const int y0 = ty*2, x0 = tx*2;
  for (int ci0 = 0; ci0 < Cin; ci0 += 8){
    const int cic = (Cin - ci0 < 8) ? (Cin - ci0) : 8;
    const int tot = cic*1156;
    for (int e = tid; e < tot; e += 256){
      int c = e / 1156; int r = e - c*1156;
      int lh = r / 34, lw = r - lh*34;
      int ih = h0 + lh - 1, iw = w0 + lw - 1;
      float v = 0.f;
      if ((unsigned)ih < (unsigned)H && (unsigned)iw < (unsigned)W)
        v = in[((size_t)(b*Cin + ci0 + c)*H + ih)*W + iw];
      s_in[c][lh][lw] = v;
    }
    const int wtot = COT*cic*9;
    for (int e = tid; e < wtot; e += 256){
      int o = e / (cic*9); int r = e - o*(cic*9);
      int c = r / 9, t = r - c*9;
      int co = co0 + o;
      float v = 0.f;
      if (co < Cout) v = wgt[(size_t)(co*Cin + ci0 + c)*9 + t];
      s_w[o][c][t] = v;
    }
    __syncthreads();
    for (int c = 0; c < cic; ++c){
      float p[4][4];
      #pragma unroll
      for (int r=0;r<4;r++)
        #pragma unroll
        for (int s=0;s<4;s++)
          p[r][s] = s_in[c][y0+r][x0+s];
      #pragma unroll
      for (int dh=0; dh<3; dh++)
        #pragma unroll
        for (int dw=0; dw<3; dw++){
          #pragma unroll
          for (int o=0;o<COT;o++){
            float wv = s_w[o][c][dh*3+dw];
            acc[o][0][0] = fmaf(p[dh  ][dw  ], wv, acc[o][0][0]);
            acc[o][0][1] = fmaf(p[dh  ][dw+1], wv, acc[o][0][1]);
            acc[o][1][0] = fmaf(p[dh+1][dw  ], wv, acc[o][1][0]);
            acc[o][1][1] = fmaf(p[dh+1][dw+1], wv, acc[o][1][1]);
          }
        }
    }
    __syncthreads();
  }
  #pragma unroll
  for (int o=0;o<COT;o++){
    int co = co0 + o;
    if (co >= Cout) continue;
    float bv = bias[co];
    #pragma unroll
    for (int r=0;r<2;r++)
      #pragma unroll
      for (int s=0;s<2;s++){
        float v = acc[o][r][s] + bv;
        if (relu) v = fmaxf(v, 0.f);
        out[((size_t)(b*Cout + co)*H + h0+y0+r)*W + w0+x0+s] = v;
      }
  }
}

__global__ __launch_bounds__(256) void pool2k(const float* __restrict__ in, float* __restrict__ out,
                                              int n, int Ho, int Wo){
  int idx = blockIdx.x*256 + threadIdx.x;
  if (idx >= n) return;
  int wo = idx % Wo; int t = idx / Wo; int ho = t % Ho; int bc = t / Ho;
  const float* p = in + ((size_t)bc*(Ho*2) + ho*2)*(size_t)(Wo*2) + (size_t)wo*2;
  out[idx] = 0.25f*(p[0] + p[1] + p[2*Wo] + p[2*Wo+1]);
}

__global__ __launch_bounds__(256) void up2k(const float* __restrict__ in, float* __restrict__ out,
                                            int n, int Ho, int Wo){
  int idx = blockIdx.x*256 + threadIdx.x;
  if (idx >= n) return;
  int wo = idx % Wo; int t = idx / Wo; int ho = t % Ho; int bc = t / Ho;
  int Hi = Ho >> 1, Wi = Wo >> 1;
  out[idx] = in[((size_t)bc*Hi + (ho>>1))*Wi + (wo>>1)];
}

// per-(b,c) spatial mean & std (ddof=0)
__global__ __launch_bounds__(256) void statsk(const float* __restrict__ x, int HW,
                                              float* __restrict__ mo, float* __restrict__ so){
  int bc = blockIdx.x, tid = threadIdx.x;
  const float* p = x + (size_t)bc*HW;
  double s = 0.0, s2 = 0.0;
  for (int i = tid; i < HW; i += 256){ double v = p[i]; s += v; s2 += v*v; }
  __shared__ double sh[256], sh2[256];
  sh[tid] = s; sh2[tid] = s2; __syncthreads();
  for (int k=128;k>0;k>>=1){ if (tid<k){ sh[tid]+=sh[tid+k]; sh2[tid]+=sh2[tid+k]; } __syncthreads(); }
  if (tid == 0){
    double m = sh[0]/HW;
    double var = sh2[0]/HW - m*m;
    if (var < 0.0) var = 0.0;
    mo[bc] = (float)m;
    so[bc] = (float)sqrt(var);
  }
}

// f4 (C-major, per image 512x1024) -> ptsT [8][1024][512]
__global__ __launch_bounds__(256) void transposek(const float* __restrict__ f4c,
                                                  const float* __restrict__ f4s,
                                                  float* __restrict__ ptsT){
  __shared__ float t[32][33];
  int r = blockIdx.z;
  const float* src = (r < 4) ? (f4c + (size_t)r*524288) : (f4s + (size_t)(r-4)*524288);
  int n0 = blockIdx.x*32, c0 = blockIdx.y*32;
  int lx = threadIdx.x & 31, ly = threadIdx.x >> 5;
  for (int j=0;j<32;j+=8)
    t[ly+j][lx] = src[(size_t)(c0+ly+j)*1024 + n0+lx];
  __syncthreads();
  for (int j=0;j<32;j+=8)
    ptsT[((size_t)r*1024 + n0+ly+j)*512 + c0+lx] = t[lx][ly+j];
}

__global__ __launch_bounds__(256) void initcentk(const float* __restrict__ ptsT, float* __restrict__ cent){
  int i = blockIdx.x*256 + threadIdx.x;
  if (i >= 12288) return;
  int c = i & 511; int k = (i >> 9) % 3; int r = i / 1536;
  cent[i] = ptsT[((size_t)r*1024 + k)*512 + c];
}

// one wave per point; first-min argmin (matches jnp.argmin)
__global__ __launch_bounds__(256) void assignk(const float* __restrict__ ptsT,
                                               const float* __restrict__ cent, int* __restrict__ a){
  int gp = blockIdx.x*4 + (threadIdx.x >> 6);
  int lane = threadIdx.x & 63;
  int r = gp >> 10;
  const float* p = ptsT + (size_t)gp*512;
  const float* ce = cent + r*1536;
  float d0=0.f,d1=0.f,d2=0.f;
  #pragma unroll
  for (int i=0;i<8;i++){
    int c = lane + i*64;
    float v = p[c];
    float e0 = v - ce[c], e1 = v - ce[512+c], e2 = v - ce[1024+c];
    d0 = fmaf(e0,e0,d0); d1 = fmaf(e1,e1,d1); d2 = fmaf(e2,e2,d2);
  }
  #pragma unroll
  for (int off=32; off>0; off>>=1){
    d0 += __shfl_down(d0, off, 64);
    d1 += __shfl_down(d1, off, 64);
    d2 += __shfl_down(d2, off, 64);
  }
  if (lane == 0){
    int bi = 0; float bd = d0;
    if (d1 < bd){ bd = d1; bi = 1; }
    if (d2 < bd){ bd = d2; bi = 2; }
    a[gp] = bi;
  }
}

__global__ __launch_bounds__(512) void updatek(const float* __restrict__ ptsT,
                                               const int* __restrict__ a, float* __restrict__ cent){
  int r = blockIdx.x; int c = threadIdx.x;
  __shared__ int sa[1024];
  sa[c] = a[r*1024 + c]; sa[c+512] = a[r*1024 + c + 512];
  __syncthreads();
  const float* base = ptsT + (size_t)r*524288;
  float s0=0.f,s1=0.f,s2=0.f; int n0=0,n1=0,n2=0;
  for (int n=0;n<1024;n++){
    int an = sa[n];
    float v = base[(size_t)n*512 + c];
    if (an==0){ s0+=v; n0++; }
    else if (an==1){ s1+=v; n1++; }
    else { s2+=v; n2++; }
  }
  cent[r*1536 + c]        = s0/((float)n0 + 1e-6f);
  cent[r*1536 + 512 + c]  = s1/((float)n1 + 1e-6f);
  cent[r*1536 + 1024 + c] = s2/((float)n2 + 1e-6f);
}

__global__ __launch_bounds__(512) void muk(const float* __restrict__ ptsT, const int* __restrict__ a,
                                           float* __restrict__ mu, float* __restrict__ counts){
  int r = blockIdx.x; int c = threadIdx.x;
  __shared__ int sa[1024];
  sa[c] = a[r*1024 + c]; sa[c+512] = a[r*1024 + c + 512];
  __syncthreads();
  const float* base = ptsT + (size_t)r*524288;
  float s0=0.f,s1=0.f,s2=0.f; int n0=0,n1=0,n2=0;
  for (int n=0;n<1024;n++){
    int an = sa[n];
    float v = base[(size_t)n*512 + c];
    if (an==0){ s0+=v; n0++; }
    else if (an==1){ s1+=v; n1++; }
    else { s2+=v; n2++; }
  }
  int cs = r >> 2, img = r & 3;
  int i0 = cs*12 + img*3;
  mu[(size_t)(i0+0)*512 + c] = s0/((float)n0 + 1e-6f);
  mu[(size_t)(i0+1)*512 + c] = s1/((float)n1 + 1e-6f);
  mu[(size_t)(i0+2)*512 + c] = s2/((float)n2 + 1e-6f);
  if (c == 0){ counts[i0]=(float)n0; counts[i0+1]=(float)n1; counts[i0+2]=(float)n2; }
}

// 24 masked covariances: Y[z] = cov + 0.1 I   (z = cs*12 + img*3 + k)
__global__ __launch_bounds__(256) void covk(const float* __restrict__ f4c, const float* __restrict__ f4s,
        const int* __restrict__ a, const float* __restrict__ mu,
        const float* __restrict__ counts, float* __restrict__ Y){
  int z = blockIdx.z;
  int cs = z / 12; int rem = z - cs*12; int img = rem / 3; int k = rem - img*3;
  const float* pts = (cs ? f4s : f4c) + (size_t)img*524288;
  const int* an = a + (cs*4 + img)*1024;
  const float* m = mu + (size_t)z*512;
  float nc = counts[z] + 1e-6f;
  int I = blockIdx.y*64, J = blockIdx.x*64;
  __shared__ float SI[32][65], SJ[32][65];
  int tid = threadIdx.x;
  int tx = tid & 15, ty = tid >> 4;
  float acc[4][4] = {};
  for (int n0 = 0; n0 < 1024; n0 += 32){
    for (int e = tid; e < 2048; e += 256){
      int i = e >> 5, nn = e & 31;
      int n = n0 + nn;
      float msk = (an[n] == k) ? 1.f : 0.f;
      SI[nn][i] = msk * (pts[(size_t)(I+i)*1024 + n] - m[I+i]);
    }
    for (int e = tid; e < 2048; e += 256){
      int j = e >> 5, nn = e & 31;
      int n = n0 + nn;
      float msk = (an[n] == k) ? 1.f : 0.f;
      SJ[nn][j] = msk * (pts[(size_t)(J+j)*1024 + n] - m[J+j]);
    }
    __syncthreads();
    #pragma unroll 8
    for (int nn=0; nn<32; nn++){
      float ri[4], rj[4];
      #pragma unroll
      for (int q=0;q<4;q++){ ri[q] = SI[nn][ty*4+q]; rj[q] = SJ[nn][tx*4+q]; }
      #pragma unroll
      for (int qi=0;qi<4;qi++)
        #pragma unroll
        for (int qj=0;qj<4;qj++)
          acc[qi][qj] = fmaf(ri[qi], rj[qj], acc[qi][qj]);
    }
    __syncthreads();
  }
  float inv = 1.f/nc;
  #pragma unroll
  for (int qi=0;qi<4;qi++){
    int gi = I + ty*4 + qi;
    #pragma unroll
    for (int qj=0;qj<4;qj++){
      int gj = J + tx*4 + qj;
      Y[(size_t)z*MSZ + (size_t)gi*512 + gj] = acc[qi][qj]*inv + ((gi==gj)?0.1f:0.f);
    }
  }
}

// power iteration for lambda_max (uses bitwise symmetry for coalesced reads)
__global__ __launch_bounds__(256) void powk(const float* __restrict__ Y, float* __restrict__ sval){
  int z = blockIdx.x, tid = threadIdx.x;
  const float* M = Y + (size_t)z*MSZ;
  __shared__ float v[512];
  __shared__ float red[256];
  __shared__ float nrmsh;
  v[tid] = 1.f; v[tid+256] = 1.f;
  __syncthreads();
  float lastn = 0.1f;
  for (int it=0; it<10; ++it){
    float y0=0.f, y1=0.f;
    for (int c=0;c<512;c++){
      float vc = v[c];
      y0 = fmaf(M[(size_t)c*512 + tid      ], vc, y0);
      y1 = fmaf(M[(size_t)c*512 + tid + 256], vc, y1);
    }
    red[tid] = y0*y0 + y1*y1;
    __syncthreads();
    for (int s=128;s>0;s>>=1){ if (tid<s) red[tid]+=red[tid+s]; __syncthreads(); }
    if (tid==0) nrmsh = sqrtf(red[0]) + 1e-30f;
    __syncthreads();
    float nrm = nrmsh;
    v[tid] = y0/nrm; v[tid+256] = y1/nrm;
    lastn = nrm;
    __syncthreads();
  }
  if (tid==0) sval[z] = lastn*1.05f + 1e-12f;
}

__global__ __launch_bounds__(256) void nsinitk(float* __restrict__ Y, float* __restrict__ Z,
                                               const float* __restrict__ sval){
  size_t idx = (size_t)blockIdx.x*256 + threadIdx.x;
  if (idx >= (size_t)24*MSZ) return;
  int z = (int)(idx >> 18);
  int rc = (int)(idx & (MSZ-1));
  int rr = rc >> 9, cc = rc & 511;
  Y[idx] *= 1.f / sval[z];
  Z[idx] = (rr==cc) ? 1.f : 0.f;
}

// batched 64x64-tile fp32 GEMM; TRANS=1: A'=(3I-A)/2, TRANS=2: B'=(3I-B)/2
template<int TRANS>
__global__ __launch_bounds__(256) void bmmk(const float* __restrict__ A, const float* __restrict__ B,
        float* __restrict__ C, int M, int N, int K,
        long long sA, long long sB, long long sC, int bdiv, const float* __restrict__ scale)
{
  int bz = blockIdx.z;
  const float* Ab = A + (size_t)bz*sA;
  const float* Bb = B + (size_t)(bz/bdiv)*sB;
  float* Cb = C + (size_t)bz*sC;
  int m0 = blockIdx.y << 6, n0 = blockIdx.x << 6;
  int tid = threadIdx.x;
  int tx = tid & 15, ty = tid >> 4;
  __shared__ float As[16][65], Bs[16][65];
  float acc[4][4] = {};
  for (int k0=0; k0<K; k0+=16){
    for (int e = tid; e < 1024; e += 256){
      int kk = e & 15, m = e >> 4;
      float v = Ab[(size_t)(m0+m)*K + (k0+kk)];
      if (TRANS==1) v = 1.5f*(((k0+kk)==(m0+m)) ? 1.f : 0.f) - 0.5f*v;
      As[kk][m] = v;
    }
    for (int e = tid; e < 1024; e += 256){
      int nn = e & 63, kk = e >> 6;
      float v = Bb[(size_t)(k0+kk)*N + (n0+nn)];
      if (TRANS==2) v = 1.5f*(((k0+kk)==(n0+nn)) ? 1.f : 0.f) - 0.5f*v;
      Bs[kk][nn] = v;
    }
    __syncthreads();
    #pragma unroll
    for (int kk=0;kk<16;kk++){
      float a4[4], b4[4];
      #pragma unroll
      for (int q=0;q<4;q++){ a4[q]=As[kk][ty*4+q]; b4[q]=Bs[kk][tx*4+q]; }
      #pragma unroll
      for (int i=0;i<4;i++)
        #pragma unroll
        for (int j=0;j<4;j++)
          acc[i][j] = fmaf(a4[i], b4[j], acc[i][j]);
    }
    __syncthreads();
  }
  float scv = scale ? scale[bz] : 1.0f;
  #pragma unroll
  for (int i=0;i<4;i++){
    int m = m0 + ty*4 + i;
    #pragma unroll
    for (int j=0;j<4;j++)
      Cb[(size_t)m*N + n0 + tx*4 + j] = acc[i][j]*scv;
  }
}

__global__ void make_scalesk(const float* __restrict__ sval, float* __restrict__ scl){
  int i = threadIdx.x;
  if (i < 12) scl[i] = sqrtf(sval[12+i] / sval[i]);
}

// tvec[b] = mu_s[b] - T[b] @ mu_c[b]
__global__ __launch_bounds__(512) void tveck(const float* __restrict__ Tmat,
                                             const float* __restrict__ mu, float* __restrict__ tvec){
  int b = blockIdx.x; int c = threadIdx.x;
  __shared__ float mc[512];
  mc[c] = mu[(size_t)b*512 + c];
  __syncthreads();
  const float* Trow = Tmat + ((size_t)b*512 + c)*512;
  float s = 0.f;
  for (int d=0; d<512; d++) s = fmaf(Trow[d], mc[d], s);
  tvec[b*512 + c] = mu[(size_t)(12+b)*512 + c] - s;
}

__global__ __launch_bounds__(256) void selectk(const float* __restrict__ tpts, const float* __restrict__ tvec,
        const int* __restrict__ a, const float* __restrict__ f4c, float* __restrict__ tf){
  size_t idx = (size_t)blockIdx.x*256 + threadIdx.x;
  if (idx >= 2097152ul) return;
  int n = (int)(idx & 1023);
  int c = (int)((idx >> 10) & 511);
  int img = (int)(idx >> 19);
  int k = a[img*1024 + n];
  int b = img*3 + k;
  float v = tpts[((size_t)b*512 + c)*1024 + n] + tvec[b*512 + c];
  tf[idx] = 0.6f*v + 0.4f*f4c[idx];
}

__global__ __launch_bounds__(256) void clossk(const float* __restrict__ x, const float* __restrict__ y,
                                              int n, float* __restrict__ acc){
  int tid = threadIdx.x;
  float s = 0.f;
  for (size_t i = (size_t)blockIdx.x*256 + tid; i < (size_t)n; i += (size_t)gridDim.x*256){
    float d = x[i] - y[i]; s = fmaf(d, d, s);
  }
  __shared__ float sh[256];
  sh[tid] = s; __syncthreads();
  for (int k=128;k>0;k>>=1){ if (tid<k) sh[tid]+=sh[tid+k]; __syncthreads(); }
  if (tid==0) atomicAdd(acc, sh[0]);
}

__global__ __launch_bounds__(256) void finalk(const float* __restrict__ sm, float* __restrict__ out){
  int tid = threadIdx.x;
  const int cnts[4] = {256,512,1024,2048};
  const int offs[4] = {0,256,768,1792};
  const float* mS = sm + SM_STATS_S;
  const float* sS = sm + SM_STATS_S + 3840;
  const float* mD = sm + SM_STATS_D;
  const float* sD = sm + SM_STATS_D + 3840;
  double sl = 0.0;
  for (int L=0; L<4; ++L){
    int cnt = cnts[L], off = offs[L];
    double inv = 1.0/cnt;
    for (int i=tid; i<cnt; i+=256){
      double dm = (double)mD[off+i] - (double)mS[off+i];
      double ds = (double)sD[off+i] - (double)sS[off+i];
      sl += (dm*dm + ds*ds)*inv;
    }
  }
  __shared__ double sh[256];
  sh[tid] = sl; __syncthreads();
  for (int k=128;k>0;k>>=1){ if (tid<k) sh[tid]+=sh[tid+k]; __syncthreads(); }
  if (tid==0){
    double closs = (double)sm[SM_CLOSS] / 2097152.0;
    out[0] = (float)(closs + 0.01*sh[0]);
  }
}

// ---------------- host ----------------

extern "C" void kernel_launch(void* const* d_in, const int* in_sizes, int n_in,
                              void* d_out, int out_size, void* d_ws, size_t ws_size,
                              hipStream_t stream)
{
  const float* content = (const float*)d_in[0];
  const float* style   = (const float*)d_in[1];
  const float* Wm[8]; const float* Bm[8];
  for (int i=0;i<8;i++){ Wm[i] = (const float*)d_in[2+2*i]; Bm[i] = (const float*)d_in[3+2*i]; }
  float* out = (float*)d_out;
  float* ws = (float*)d_ws;

  float* f4c  = ws + OFF_F4C;
  float* f4s  = ws + OFF_F4S;
  float* tf   = ws + OFF_TF;
  float* dec  = ws + OFF_DEC;
  float* Tmat = ws + OFF_TMAT;
  float* sm   = ws + OFF_SMALL;
  float* AR   = ws + OFF_ARENA;
  int*   aPtr = (int*)(sm + SM_ASSIGN);
  float* cent = sm + SM_CENT;
  float* mu   = sm + SM_MU;
  float* counts = sm + SM_COUNTS;
  float* sval = sm + SM_SVAL;
  float* scl  = sm + SM_SCALE;
  float* tvec = sm + SM_TVEC;
  float* ptsT = AR + 25165824ul;   // overlaps Mb region (dead by the time Mb is written)

  zerok<<<512,256,0,stream>>>(sm, 131072);

  auto conv = [&](const float* inp, int li, float* outp, int Ci,int Co,int H,int Wd,int relu,int cot){
    dim3 g((H>>5)*(Wd>>5), (Co + cot - 1)/cot, 4);
    if (cot==8) conv3x3<8><<<g,256,0,stream>>>(inp,Wm[li],Bm[li],outp,4,Ci,Co,H,Wd,relu);
    else        conv3x3<4><<<g,256,0,stream>>>(inp,Wm[li],Bm[li],outp,4,Ci,Co,H,Wd,relu);
  };
  auto pool = [&](const float* inp, float* outp, int C,int Ho,int Wo){
    int n = 4*C*Ho*Wo;
    pool2k<<<(n+255)/256,256,0,stream>>>(inp,outp,n,Ho,Wo);
  };
  auto up = [&](const float* inp, float* outp, int C,int Ho,int Wo){
    int n = 4*C*Ho*Wo;
    up2k<<<(n+255)/256,256,0,stream>>>(inp,outp,n,Ho,Wo);
  };

  // encode scratch (arena)
  float* F1 = AR + 0;
  float* P1 = AR + 16777216ul;
  float* F2 = AR + 0;
  float* P2 = AR + 8388608ul;
  float* F3 = AR + 10485760ul;
  float* P3 = AR + 0;

  // ---- content encode ----
  conv(content, 0, F1, 3,64,256,256,1,8);
  pool(F1,P1,64,128,128);
  conv(P1,1,F2, 64,128,128,128,1,8);
  pool(F2,P2,128,64,64);
  conv(P2,2,F3, 128,256,64,64,1,8);
  pool(F3,P3,256,32,32);
  conv(P3,3,f4c, 256,512,32,32,1,4);

  // ---- style encode + stats ----
  float* mS = sm + SM_STATS_S;
  float* sS = sm + SM_STATS_S + 3840;
  conv(style, 0, F1, 3,64,256,256,1,8);
  statsk<<<256,256,0,stream>>>(F1,65536, mS+0, sS+0);
  pool(F1,P1,64,128,128);
  conv(P1,1,F2, 64,128,128,128,1,8);
  statsk<<<512,256,0,stream>>>(F2,16384, mS+256, sS+256);
  pool(F2,P2,128,64,64);
  conv(P2,2,F3, 128,256,64,64,1,8);
  statsk<<<1024,256,0,stream>>>(F3,4096, mS+768, sS+768);
  pool(F3,P3,256,32,32);
  conv(P3,3,f4s, 256,512,32,32,1,4);
  statsk<<<2048,256,0,stream>>>(f4s,1024, mS+1792, sS+1792);

  // ---- k-means (content r=0..3, style r=4..7) ----
  transposek<<<dim3(32,16,8),256,0,stream>>>(f4c,f4s,ptsT);
  initcentk<<<48,256,0,stream>>>(ptsT,cent);
  for (int it=0; it<10; ++it){
    assignk<<<2048,256,0,stream>>>(ptsT,cent,aPtr);
    updatek<<<8,512,0,stream>>>(ptsT,aPtr,cent);
  }
  assignk<<<2048,256,0,stream>>>(ptsT,cent,aPtr);
  muk<<<8,512,0,stream>>>(ptsT,aPtr,mu,counts);

  // ---- covariances + Newton-Schulz sqrt/invsqrt ----
  float* Yb = AR + 0;
  float* Zb = AR + 6291456ul;
  float* Y2 = AR + 12582912ul;
  float* Z2 = AR + 18874368ul;
  float* Mb = AR + 25165824ul;
  covk<<<dim3(8,8,24),256,0,stream>>>(f4c,f4s,aPtr,mu,counts,Yb);
  powk<<<24,256,0,stream>>>(Yb,sval);
  nsinitk<<<24576,256,0,stream>>>(Yb,Zb,sval);
  float* Yc=Yb; float* Zc=Zb; float* Ya=Y2; float* Za=Z2;
  for (int it=0; it<NS_ITERS; ++it){
    bmmk<0><<<dim3(8,8,24),256,0,stream>>>(Zc,Yc,Mb,512,512,512,(long long)MSZ,(long long)MSZ,(long long)MSZ,1,nullptr);
    bmmk<2><<<dim3(8,8,24),256,0,stream>>>(Yc,Mb,Ya,512,512,512,(long long)MSZ,(long long)MSZ,(long long)MSZ,1,nullptr);
    bmmk<1><<<dim3(8,8,24),256,0,stream>>>(Mb,Zc,Za,512,512,512,(long long)MSZ,(long long)MSZ,(long long)MSZ,1,nullptr);
    float* t1=Yc; Yc=Ya; Ya=t1;
    float* t2=Zc; Zc=Za; Za=t2;
  }
  // T[b] = sqrt(s_s/s_c) * Y_style[b] @ Z_content[b]
  make_scalesk<<<1,64,0,stream>>>(sval,scl);
  bmmk<0><<<dim3(8,8,12),256,0,stream>>>(Yc+(size_t)12*MSZ, Zc, Tmat, 512,512,512,
                                         (long long)MSZ,(long long)MSZ,(long long)MSZ,1,scl);
  tveck<<<12,512,0,stream>>>(Tmat,mu,tvec);
  // tpts[b] = T[b] @ f[img]   (b = img*3+k)
  bmmk<0><<<dim3(16,8,12),256,0,stream>>>(Tmat, f4c, Mb, 512,1024,512,
                                          (long long)MSZ,524288ll,524288ll,3,nullptr);
  selectk<<<8192,256,0,stream>>>(Mb,tvec,aPtr,f4c,tf);

  // ---- decode ----
  float* X1 = AR + 0;
  float* U1 = AR + 1048576ul;
  float* X2 = AR + 5242880ul;
  float* U2 = AR + 7340032ul;
  float* X3 = AR + 0;
  float* U3 = AR + 4194304ul;
  conv(tf, 4, X1, 512,256,32,32,1,4);
  up(X1,U1,256,64,64);
  conv(U1,5,X2, 256,128,64,64,1,4);
  up(X2,U2,128,128,128);
  conv(U2,6,X3, 128,64,128,128,1,8);
  up(X3,U3,64,256,256);
  conv(U3,7,dec, 64,3,256,256,0,4);

  // ---- decoded encode + stats + content loss ----
  float* mD = sm + SM_STATS_D;
  float* sD = sm + SM_STATS_D + 3840;
  conv(dec, 0, F1, 3,64,256,256,1,8);
  statsk<<<256,256,0,stream>>>(F1,65536, mD+0, sD+0);
  pool(F1,P1,64,128,128);
  conv(P1,1,F2, 64,128,128,128,1,8);
  statsk<<<512,256,0,stream>>>(F2,16384, mD+256, sD+256);
  pool(F2,P2,128,64,64);
  conv(P2,2,F3, 128,256,64,64,1,8);
  statsk<<<1024,256,0,stream>>>(F3,4096, mD+768, sD+768);
  pool(F3,P3,256,32,32);
  conv(P3,3,tf, 256,512,32,32,1,4);   // f4(dec) reuses tf buffer
  statsk<<<2048,256,0,stream>>>(tf,1024, mD+1792, sD+1792);
  clossk<<<2048,256,0,stream>>>(tf,f4c,2097152, sm+SM_CLOSS);
  finalk<<<1,256,0,stream>>>(sm,out);
}

// Round 2
// 9836.739 us; speedup vs baseline: 1.5865x; 1.5865x over previous
//
#include <hip/hip_runtime.h>
#include <cstddef>

#define NS_ITERS 12
#define MSZ 262144  // 512*512

// ---------------- workspace offsets (in floats) ----------------
#define OFF_F4C   0ul
#define OFF_F4S   2097152ul
#define OFF_TF    4194304ul      // tf_ during style transfer; f4(dec) at the end
#define OFF_DEC   6291456ul      // 786432
#define OFF_TMAT  7077888ul      // 12*512*512
#define OFF_SMALL 10223616ul     // 131072 floats of small stuff (zeroed each launch)
#define OFF_ARENA 10354688ul     // 31457280 floats reusable arena
// total: 41,811,968 floats = ~167 MB

// SMALL sub-offsets (floats)
#define SM_CENT    0       // 8*3*512
#define SM_ASSIGN  12288   // 8*1024 ints
#define SM_MU      20480   // 24*512
#define SM_COUNTS  32768   // 24
#define SM_SVAL    32800   // 24
#define SM_SCALE   32832   // 12
#define SM_TVEC    32864   // 12*512
#define SM_STATS_S 39008   // style stats: mean[3840] then std[3840]
#define SM_STATS_D 46688   // decoded stats: same layout
#define SM_CLOSS   54368   // 1
#define SM_G       54400   // 24  (gamma^2 per NS batch)
#define SM_OS      54432   // 24  (gamma/2 per NS batch)

// ---------------- kernels ----------------

__global__ __launch_bounds__(256) void zerok(float* p, int n){
  int i = blockIdx.x*256 + threadIdx.x;
  if (i < n) p[i] = 0.f;
}

// direct 3x3 SAME conv, NCHW. 32x32 spatial tile, 256 thr (2x2 px each), COT couts/block, 8-ci chunks.
template<int COT>
__global__ __launch_bounds__(256) void conv3x3(
    const float* __restrict__ in, const float* __restrict__ wgt,
    const float* __restrict__ bias, float* __restrict__ out,
    int B, int Cin, int Cout, int H, int W, int relu)
{
  __shared__ float s_in[8][34][34];
  __shared__ float s_w[COT][8][9];
  const int tid = threadIdx.x;
  const int tx = tid & 15, ty = tid >> 4;
  const int tilesW = W >> 5;
  const int h0 = (blockIdx.x / tilesW) << 5;
  const int w0 = (blockIdx.x % tilesW) << 5;
  const int co0 = blockIdx.y * COT;
  const int b = blockIdx.z;
  float acc[COT][2][2];
  #pragma unroll
  for (int o=0;o<COT;o++){acc[o][0][0]=0.f;acc[o][0][1]=0.f;acc[o][1][0]=0.f;acc[o][1][1]=0.f;}
  const int y0 = ty*2, x0 = tx*2;
  for (int ci0 = 0; ci0 < Cin; ci0 += 8){
    const int cic = (Cin - ci0 < 8) ? (Cin - ci0) : 8;
    const int tot = cic*1156;
    for (int e = tid; e < tot; e += 256){
      int c = e / 1156; int r = e - c*1156;
      int lh = r / 34, lw = r - lh*34;
      int ih = h0 + lh - 1, iw = w0 + lw - 1;
      float v = 0.f;
      if ((unsigned)ih < (unsigned)H && (unsigned)iw < (unsigned)W)
        v = in[((size_t)(b*Cin + ci0 + c)*H + ih)*W + iw];
      s_in[c][lh][lw] = v;
    }
    const int wtot = COT*cic*9;
    for (int e = tid; e < wtot; e += 256){
      int o = e / (cic*9); int r = e - o*(cic*9);
      int c = r / 9, t = r - c*9;
      int co = co0 + o;
      float v = 0.f;
      if (co < Cout) v = wgt[(size_t)(co*Cin + ci0 + c)*9 + t];
      s_w[o][c][t] = v;
    }
    __syncthreads();
    for (int c = 0; c < cic; ++c){
      float p[4][4];
      #pragma unroll
      for (int r=0;r<4;r++)
        #pragma unroll
        for (int s=0;s<4;s++)
          p[r][s] = s_in[c][y0+r][x0+s];
      #pragma unroll
      for (int dh=0; dh<3; dh++)
        #pragma unroll
        for (int dw=0; dw<3; dw++){
          #pragma unroll
          for (int o=0;o<COT;o++){
            float wv = s_w[o][c][dh*3+dw];
            acc[o][0][0] = fmaf(p[dh  ][dw  ], wv, acc[o][0][0]);
            acc[o][0][1] = fmaf(p[dh  ][dw+1], wv, acc[o][0][1]);
            acc[o][1][0] = fmaf(p[dh+1][dw  ], wv, acc[o][1][0]);
            acc[o][1][1] = fmaf(p[dh+1][dw+1], wv, acc[o][1][1]);
          }
        }
    }
    __syncthreads();
  }
  #pragma unroll
  for (int o=0;o<COT;o++){
    int co = co0 + o;
    if (co >= Cout) continue;
    float bv = bias[co];
    #pragma unroll
    for (int r=0;r<2;r++)
      #pragma unroll
      for (int s=0;s<2;s++){
        float v = acc[o][r][s] + bv;
        if (relu) v = fmaxf(v, 0.f);
        out[((size_t)(b*Cout + co)*H + h0+y0+r)*W + w0+x0+s] = v;
      }
  }
}

__global__ __launch_bounds__(256) void pool2k(const float* __restrict__ in, float* __restrict__ out,
                                              int n, int Ho, int Wo){
  int idx = blockIdx.x*256 + threadIdx.x;
  if (idx >= n) return;
  int wo = idx % Wo; int t = idx / Wo; int ho = t % Ho; int bc = t / Ho;
  const float* p = in + ((size_t)bc*(Ho*2) + ho*2)*(size_t)(Wo*2) + (size_t)wo*2;
  out[idx] = 0.25f*(p[0] + p[1] + p[2*Wo] + p[2*Wo+1]);
}

__global__ __launch_bounds__(256) void up2k(const float* __restrict__ in, float* __restrict__ out,
                                            int n, int Ho, int Wo){
  int idx = blockIdx.x*256 + threadIdx.x;
  if (idx >= n) return;
  int wo = idx % Wo; int t = idx / Wo; int ho = t % Ho; int bc = t / Ho;
  int Hi = Ho >> 1, Wi = Wo >> 1;
  out[idx] = in[((size_t)bc*Hi + (ho>>1))*Wi + (wo>>1)];
}

// per-(b,c) spatial mean & std (ddof=0)
__global__ __launch_bounds__(256) void statsk(const float* __restrict__ x, int HW,
                                              float* __restrict__ mo, float* __restrict__ so){
  int bc = blockIdx.x, tid = threadIdx.x;
  const float* p = x + (size_t)bc*HW;
  double s = 0.0, s2 = 0.0;
  for (int i = tid; i < HW; i += 256){ double v = p[i]; s += v; s2 += v*v; }
  __shared__ double sh[256], sh2[256];
  sh[tid] = s; sh2[tid] = s2; __syncthreads();
  for (int k=128;k>0;k>>=1){ if (tid<k){ sh[tid]+=sh[tid+k]; sh2[tid]+=sh2[tid+k]; } __syncthreads(); }
  if (tid == 0){
    double m = sh[0]/HW;
    double var = sh2[0]/HW - m*m;
    if (var < 0.0) var = 0.0;
    mo[bc] = (float)m;
    so[bc] = (float)sqrt(var);
  }
}

// f4 (C-major, per image 512x1024) -> ptsT [8][1024][512]
__global__ __launch_bounds__(256) void transposek(const float* __restrict__ f4c,
                                                  const float* __restrict__ f4s,
                                                  float* __restrict__ ptsT){
  __shared__ float t[32][33];
  int r = blockIdx.z;
  const float* src = (r < 4) ? (f4c + (size_t)r*524288) : (f4s + (size_t)(r-4)*524288);
  int n0 = blockIdx.x*32, c0 = blockIdx.y*32;
  int lx = threadIdx.x & 31, ly = threadIdx.x >> 5;
  for (int j=0;j<32;j+=8)
    t[ly+j][lx] = src[(size_t)(c0+ly+j)*1024 + n0+lx];
  __syncthreads();
  for (int j=0;j<32;j+=8)
    ptsT[((size_t)r*1024 + n0+ly+j)*512 + c0+lx] = t[lx][ly+j];
}

__global__ __launch_bounds__(256) void initcentk(const float* __restrict__ ptsT, float* __restrict__ cent){
  int i = blockIdx.x*256 + threadIdx.x;
  if (i >= 12288) return;
  int c = i & 511; int k = (i >> 9) % 3; int r = i / 1536;
  cent[i] = ptsT[((size_t)r*1024 + k)*512 + c];
}

// one wave per point; first-min argmin (matches jnp.argmin)
__global__ __launch_bounds__(256) void assignk(const float* __restrict__ ptsT,
                                               const float* __restrict__ cent, int* __restrict__ a){
  int gp = blockIdx.x*4 + (threadIdx.x >> 6);
  int lane = threadIdx.x & 63;
  int r = gp >> 10;
  const float* p = ptsT + (size_t)gp*512;
  const float* ce = cent + r*1536;
  float d0=0.f,d1=0.f,d2=0.f;
  #pragma unroll
  for (int i=0;i<8;i++){
    int c = lane + i*64;
    float v = p[c];
    float e0 = v - ce[c], e1 = v - ce[512+c], e2 = v - ce[1024+c];
    d0 = fmaf(e0,e0,d0); d1 = fmaf(e1,e1,d1); d2 = fmaf(e2,e2,d2);
  }
  #pragma unroll
  for (int off=32; off>0; off>>=1){
    d0 += __shfl_down(d0, off, 64);
    d1 += __shfl_down(d1, off, 64);
    d2 += __shfl_down(d2, off, 64);
  }
  if (lane == 0){
    int bi = 0; float bd = d0;
    if (d1 < bd){ bd = d1; bi = 1; }
    if (d2 < bd){ bd = d2; bi = 2; }
    a[gp] = bi;
  }
}

// parallel centroid update: grid (r=8, cc=16), 256 thr; thread = (partial p = tid>>5, lane c = tid&31)
// WRITE==0 -> cent[r*1536 + k*512 + c]; WRITE==1 -> mu[(i0+k)*512+c] + counts
template<int WRITE>
__global__ __launch_bounds__(256) void updatek(const float* __restrict__ ptsT,
                                               const int* __restrict__ a,
                                               float* __restrict__ dst,
                                               float* __restrict__ counts){
  int r = blockIdx.x, cc = blockIdx.y;
  int tid = threadIdx.x;
  int lane = tid & 31, p = tid >> 5;
  int c = cc*32 + lane;
  __shared__ int sa[1024];
  __shared__ int scnt[3];
  if (tid < 3) scnt[tid] = 0;
  for (int i = tid; i < 1024; i += 256) sa[i] = a[r*1024 + i];
  __syncthreads();
  // counts (each thread counts 4 assignments)
  {
    int l0=0,l1=0,l2=0;
    #pragma unroll
    for (int i=tid*4;i<tid*4+4;i++){ int an=sa[i]; l0+=(an==0); l1+=(an==1); l2+=(an==2); }
    if (l0) atomicAdd(&scnt[0], l0);
    if (l1) atomicAdd(&scnt[1], l1);
    if (l2) atomicAdd(&scnt[2], l2);
  }
  const float* base = ptsT + (size_t)r*524288;
  float s0=0.f,s1=0.f,s2=0.f;
  for (int n = p*128; n < p*128+128; ++n){
    float v = base[(size_t)n*512 + c];
    int an = sa[n];
    s0 += (an==0) ? v : 0.f;
    s1 += (an==1) ? v : 0.f;
    s2 += (an==2) ? v : 0.f;
  }
  __shared__ float red[8][3][32];
  red[p][0][lane]=s0; red[p][1][lane]=s1; red[p][2][lane]=s2;
  __syncthreads();
  if (p == 0){
    float t0=0.f,t1=0.f,t2=0.f;
    #pragma unroll
    for (int q=0;q<8;q++){ t0+=red[q][0][lane]; t1+=red[q][1][lane]; t2+=red[q][2][lane]; }
    float n0 = (float)scnt[0] + 1e-6f, n1 = (float)scnt[1] + 1e-6f, n2 = (float)scnt[2] + 1e-6f;
    if (WRITE == 0){
      dst[r*1536 + c]        = t0/n0;
      dst[r*1536 + 512 + c]  = t1/n1;
      dst[r*1536 + 1024 + c] = t2/n2;
    } else {
      int cs = r >> 2, img = r & 3;
      int i0 = cs*12 + img*3;
      dst[(size_t)(i0+0)*512 + c] = t0/n0;
      dst[(size_t)(i0+1)*512 + c] = t1/n1;
      dst[(size_t)(i0+2)*512 + c] = t2/n2;
      if (cc == 0 && lane == 0){
        counts[i0]   = (float)scnt[0];
        counts[i0+1] = (float)scnt[1];
        counts[i0+2] = (float)scnt[2];
      }
    }
  }
}

// 24 masked covariances: Y[z] = cov + 0.1 I   (z = cs*12 + img*3 + k)
__global__ __launch_bounds__(256) void covk(const float* __restrict__ f4c, const float* __restrict__ f4s,
        const int* __restrict__ a, const float* __restrict__ mu,
        const float* __restrict__ counts, float* __restrict__ Y){
  int z = blockIdx.z;
  int cs = z / 12; int rem = z - cs*12; int img = rem / 3; int k = rem - img*3;
  const float* pts = (cs ? f4s : f4c) + (size_t)img*524288;
  const int* an = a + (cs*4 + img)*1024;
  const float* m = mu + (size_t)z*512;
  float nc = counts[z] + 1e-6f;
  int I = blockIdx.y*64, J = blockIdx.x*64;
  __shared__ float SI[32][65], SJ[32][65];
  int tid = threadIdx.x;
  int tx = tid & 15, ty = tid >> 4;
  float acc[4][4] = {};
  for (int n0 = 0; n0 < 1024; n0 += 32){
    for (int e = tid; e < 2048; e += 256){
      int i = e >> 5, nn = e & 31;
      int n = n0 + nn;
      float msk = (an[n] == k) ? 1.f : 0.f;
      SI[nn][i] = msk * (pts[(size_t)(I+i)*1024 + n] - m[I+i]);
    }
    for (int e = tid; e < 2048; e += 256){
      int j = e >> 5, nn = e & 31;
      int n = n0 + nn;
      float msk = (an[n] == k) ? 1.f : 0.f;
      SJ[nn][j] = msk * (pts[(size_t)(J+j)*1024 + n] - m[J+j]);
    }
    __syncthreads();
    #pragma unroll 8
    for (int nn=0; nn<32; nn++){
      float ri[4], rj[4];
      #pragma unroll
      for (int q=0;q<4;q++){ ri[q] = SI[nn][ty*4+q]; rj[q] = SJ[nn][tx*4+q]; }
      #pragma unroll
      for (int qi=0;qi<4;qi++)
        #pragma unroll
        for (int qj=0;qj<4;qj++)
          acc[qi][qj] = fmaf(ri[qi], rj[qj], acc[qi][qj]);
    }
    __syncthreads();
  }
  float inv = 1.f/nc;
  #pragma unroll
  for (int qi=0;qi<4;qi++){
    int gi = I + ty*4 + qi;
    #pragma unroll
    for (int qj=0;qj<4;qj++){
      int gj = J + tx*4 + qj;
      Y[(size_t)z*MSZ + (size_t)gi*512 + gj] = acc[qi][qj]*inv + ((gi==gj)?0.1f:0.f);
    }
  }
}

// power iteration for lambda_max
__global__ __launch_bounds__(256) void powk(const float* __restrict__ Y, float* __restrict__ sval){
  int z = blockIdx.x, tid = threadIdx.x;
  const float* M = Y + (size_t)z*MSZ;
  __shared__ float v[512];
  __shared__ float red[256];
  __shared__ float nrmsh;
  v[tid] = 1.f; v[tid+256] = 1.f;
  __syncthreads();
  float lastn = 0.1f;
  for (int it=0; it<10; ++it){
    float y0=0.f, y1=0.f;
    for (int c=0;c<512;c++){
      float vc = v[c];
      y0 = fmaf(M[(size_t)c*512 + tid      ], vc, y0);
      y1 = fmaf(M[(size_t)c*512 + tid + 256], vc, y1);
    }
    red[tid] = y0*y0 + y1*y1;
    __syncthreads();
    for (int s=128;s>0;s>>=1){ if (tid<s) red[tid]+=red[tid+s]; __syncthreads(); }
    if (tid==0) nrmsh = sqrtf(red[0]) + 1e-30f;
    __syncthreads();
    float nrm = nrmsh;
    v[tid] = y0/nrm; v[tid+256] = y1/nrm;
    lastn = nrm;
    __syncthreads();
  }
  if (tid==0) sval[z] = lastn*1.05f + 1e-12f;
}

__global__ __launch_bounds__(256) void nsinitk(float* __restrict__ Y, float* __restrict__ Z,
                                               const float* __restrict__ sval){
  size_t idx = (size_t)blockIdx.x*256 + threadIdx.x;
  if (idx >= (size_t)24*MSZ) return;
  int z = (int)(idx >> 18);
  int rc = (int)(idx & (MSZ-1));
  int rr = rc >> 9, cc = rc & 511;
  Y[idx] *= 1.f / sval[z];
  Z[idx] = (rr==cc) ? 1.f : 0.f;
}

// trace-scaled NS factors: g = gamma^2 = min(512/tr(M), 2.7); os = gamma/2
__global__ __launch_bounds__(256) void scalek(const float* __restrict__ Mb,
                                              float* __restrict__ g, float* __restrict__ os){
  int z = blockIdx.x, tid = threadIdx.x;
  const float* M = Mb + (size_t)z*MSZ;
  float s = M[(size_t)tid*513] + M[(size_t)(tid+256)*513];
  __shared__ float sh[256];
  sh[tid] = s; __syncthreads();
  for (int k=128;k>0;k>>=1){ if (tid<k) sh[tid]+=sh[tid+k]; __syncthreads(); }
  if (tid==0){
    float tr = fmaxf(sh[0], 1e-6f);
    float g2 = fminf(512.f/tr, 2.7f);
    g[z] = g2;
    os[z] = 0.5f*sqrtf(g2);
  }
}

// batched fp32 GEMM: 128x64 block tile, 256 thr, 8x4 micro, float4 LDS frags.
// TRANS=1: A' = 3I - g*A ; TRANS=2: B' = 3I - g*B ; output *= osc[bz] if given.
template<int TRANS>
__global__ __launch_bounds__(256) void bmmk(const float* __restrict__ A, const float* __restrict__ B,
        float* __restrict__ C, int M, int N, int K,
        long long sA, long long sB, long long sC, int bdiv,
        const float* __restrict__ gam, const float* __restrict__ osc)
{
  int bz = blockIdx.z;
  const float* Ab = A + (size_t)bz*sA;
  const float* Bb = B + (size_t)(bz/bdiv)*sB;
  float* Cb = C + (size_t)bz*sC;
  const float g = (TRANS != 0 && gam) ? gam[bz] : 1.0f;
  const int m0 = blockIdx.y << 7, n0 = blockIdx.x << 6;
  const int tid = threadIdx.x;
  const int trow = tid >> 4;      // 0..15 -> m = trow*8
  const int tcol = tid & 15;      // 0..15 -> n = tcol*4
  __shared__ __align__(16) float As[16][132];  // [k][m]
  __shared__ __align__(16) float Bs[16][68];   // [k][n]
  float acc[8][4] = {};
  for (int k0 = 0; k0 < K; k0 += 16){
    // stage A: 128 m x 16 k (transposed into LDS); 512 float4s, 2 per thread
    #pragma unroll
    for (int l=0;l<2;l++){
      int e = tid + l*256;
      int m = e >> 2;
      int kq = (e & 3) << 2;
      float4 v4 = *(const float4*)(Ab + (size_t)(m0+m)*K + k0 + kq);
      float vv[4] = {v4.x, v4.y, v4.z, v4.w};
      #pragma unroll
      for (int j=0;j<4;j++){
        float v = vv[j];
        if (TRANS==1) v = 3.0f*((k0+kq+j)==(m0+m) ? 1.f : 0.f) - g*v;
        As[kq+j][m] = v;
      }
    }
    // stage B: 16 k x 64 n; 256 float4s, 1 per thread
    {
      int kk = tid >> 4;
      int nq = (tid & 15) << 2;
      float4 v4 = *(const float4*)(Bb + (size_t)(k0+kk)*N + n0 + nq);
      float vv[4] = {v4.x, v4.y, v4.z, v4.w};
      #pragma unroll
      for (int j=0;j<4;j++){
        if (TRANS==2) vv[j] = 3.0f*((k0+kk)==(n0+nq+j) ? 1.f : 0.f) - g*vv[j];
      }
      *(float4*)(&Bs[kk][nq]) = make_float4(vv[0],vv[1],vv[2],vv[3]);
    }
    __syncthreads();
    #pragma unroll
    for (int kk=0;kk<16;kk++){
      float a8[8];
      *(float4*)(a8)     = *(const float4*)(&As[kk][trow*8]);
      *(float4*)(a8 + 4) = *(const float4*)(&As[kk][trow*8 + 4]);
      float4 b4 = *(const float4*)(&Bs[kk][tcol*4]);
      float bb[4] = {b4.x, b4.y, b4.z, b4.w};
      #pragma unroll
      for (int i=0;i<8;i++)
        #pragma unroll
        for (int j=0;j<4;j++)
          acc[i][j] = fmaf(a8[i], bb[j], acc[i][j]);
    }
    __syncthreads();
  }
  const float sc = osc ? osc[bz] : 1.0f;
  #pragma unroll
  for (int i=0;i<8;i++){
    int m = m0 + trow*8 + i;
    float4 o = make_float4(acc[i][0]*sc, acc[i][1]*sc, acc[i][2]*sc, acc[i][3]*sc);
    *(float4*)(Cb + (size_t)m*N + n0 + tcol*4) = o;
  }
}

__global__ void make_scalesk(const float* __restrict__ sval, float* __restrict__ scl){
  int i = threadIdx.x;
  if (i < 12) scl[i] = sqrtf(sval[12+i] / sval[i]);
}

// tvec[b] = mu_s[b] - T[b] @ mu_c[b]
__global__ __launch_bounds__(512) void tveck(const float* __restrict__ Tmat,
                                             const float* __restrict__ mu, float* __restrict__ tvec){
  int b = blockIdx.x; int c = threadIdx.x;
  __shared__ float mc[512];
  mc[c] = mu[(size_t)b*512 + c];
  __syncthreads();
  const float* Trow = Tmat + ((size_t)b*512 + c)*512;
  float s = 0.f;
  for (int d=0; d<512; d++) s = fmaf(Trow[d], mc[d], s);
  tvec[b*512 + c] = mu[(size_t)(12+b)*512 + c] - s;
}

__global__ __launch_bounds__(256) void selectk(const float* __restrict__ tpts, const float* __restrict__ tvec,
        const int* __restrict__ a, const float* __restrict__ f4c, float* __restrict__ tf){
  size_t idx = (size_t)blockIdx.x*256 + threadIdx.x;
  if (idx >= 2097152ul) return;
  int n = (int)(idx & 1023);
  int c = (int)((idx >> 10) & 511);
  int img = (int)(idx >> 19);
  int k = a[img*1024 + n];
  int b = img*3 + k;
  float v = tpts[((size_t)b*512 + c)*1024 + n] + tvec[b*512 + c];
  tf[idx] = 0.6f*v + 0.4f*f4c[idx];
}

__global__ __launch_bounds__(256) void clossk(const float* __restrict__ x, const float* __restrict__ y,
                                              int n, float* __restrict__ acc){
  int tid = threadIdx.x;
  float s = 0.f;
  for (size_t i = (size_t)blockIdx.x*256 + tid; i < (size_t)n; i += (size_t)gridDim.x*256){
    float d = x[i] - y[i]; s = fmaf(d, d, s);
  }
  __shared__ float sh[256];
  sh[tid] = s; __syncthreads();
  for (int k=128;k>0;k>>=1){ if (tid<k) sh[tid]+=sh[tid+k]; __syncthreads(); }
  if (tid==0) atomicAdd(acc, sh[0]);
}

__global__ __launch_bounds__(256) void finalk(const float* __restrict__ sm, float* __restrict__ out){
  int tid = threadIdx.x;
  const int cnts[4] = {256,512,1024,2048};
  const int offs[4] = {0,256,768,1792};
  const float* mS = sm + SM_STATS_S;
  const float* sS = sm + SM_STATS_S + 3840;
  const float* mD = sm + SM_STATS_D;
  const float* sD = sm + SM_STATS_D + 3840;
  double sl = 0.0;
  for (int L=0; L<4; ++L){
    int cnt = cnts[L], off = offs[L];
    double inv = 1.0/cnt;
    for (int i=tid; i<cnt; i+=256){
      double dm = (double)mD[off+i] - (double)mS[off+i];
      double ds = (double)sD[off+i] - (double)sS[off+i];
      sl += (dm*dm + ds*ds)*inv;
    }
  }
  __shared__ double sh[256];
  sh[tid] = sl; __syncthreads();
  for (int k=128;k>0;k>>=1){ if (tid<k) sh[tid]+=sh[tid+k]; __syncthreads(); }
  if (tid==0){
    double closs = (double)sm[SM_CLOSS] / 2097152.0;
    out[0] = (float)(closs + 0.01*sh[0]);
  }
}

// ---------------- host ----------------

extern "C" void kernel_launch(void* const* d_in, const int* in_sizes, int n_in,
                              void* d_out, int out_size, void* d_ws, size_t ws_size,
                              hipStream_t stream)
{
  const float* content = (const float*)d_in[0];
  const float* style   = (const float*)d_in[1];
  const float* Wm[8]; const float* Bm[8];
  for (int i=0;i<8;i++){ Wm[i] = (const float*)d_in[2+2*i]; Bm[i] = (const float*)d_in[3+2*i]; }
  float* out = (float*)d_out;
  float* ws = (float*)d_ws;

  float* f4c  = ws + OFF_F4C;
  float* f4s  = ws + OFF_F4S;
  float* tf   = ws + OFF_TF;
  float* dec  = ws + OFF_DEC;
  float* Tmat = ws + OFF_TMAT;
  float* sm   = ws + OFF_SMALL;
  float* AR   = ws + OFF_ARENA;
  int*   aPtr = (int*)(sm + SM_ASSIGN);
  float* cent = sm + SM_CENT;
  float* mu   = sm + SM_MU;
  float* counts = sm + SM_COUNTS;
  float* sval = sm + SM_SVAL;
  float* scl  = sm + SM_SCALE;
  float* tvec = sm + SM_TVEC;
  float* gbuf = sm + SM_G;
  float* obuf = sm + SM_OS;
  float* ptsT = AR + 25165824ul;   // overlaps Mb region (dead by the time Mb is written)

  zerok<<<512,256,0,stream>>>(sm, 131072);

  auto conv = [&](const float* inp, int li, float* outp, int Ci,int Co,int H,int Wd,int relu,int cot){
    dim3 g((H>>5)*(Wd>>5), (Co + cot - 1)/cot, 4);
    if (cot==8) conv3x3<8><<<g,256,0,stream>>>(inp,Wm[li],Bm[li],outp,4,Ci,Co,H,Wd,relu);
    else        conv3x3<4><<<g,256,0,stream>>>(inp,Wm[li],Bm[li],outp,4,Ci,Co,H,Wd,relu);
  };
  auto pool = [&](const float* inp, float* outp, int C,int Ho,int Wo){
    int n = 4*C*Ho*Wo;
    pool2k<<<(n+255)/256,256,0,stream>>>(inp,outp,n,Ho,Wo);
  };
  auto up = [&](const float* inp, float* outp, int C,int Ho,int Wo){
    int n = 4*C*Ho*Wo;
    up2k<<<(n+255)/256,256,0,stream>>>(inp,outp,n,Ho,Wo);
  };

  // encode scratch (arena)
  float* F1 = AR + 0;
  float* P1 = AR + 16777216ul;
  float* F2 = AR + 0;
  float* P2 = AR + 8388608ul;
  float* F3 = AR + 10485760ul;
  float* P3 = AR + 0;

  // ---- content encode ----
  conv(content, 0, F1, 3,64,256,256,1,8);
  pool(F1,P1,64,128,128);
  conv(P1,1,F2, 64,128,128,128,1,8);
  pool(F2,P2,128,64,64);
  conv(P2,2,F3, 128,256,64,64,1,8);
  pool(F3,P3,256,32,32);
  conv(P3,3,f4c, 256,512,32,32,1,4);

  // ---- style encode + stats ----
  float* mS = sm + SM_STATS_S;
  float* sS = sm + SM_STATS_S + 3840;
  conv(style, 0, F1, 3,64,256,256,1,8);
  statsk<<<256,256,0,stream>>>(F1,65536, mS+0, sS+0);
  pool(F1,P1,64,128,128);
  conv(P1,1,F2, 64,128,128,128,1,8);
  statsk<<<512,256,0,stream>>>(F2,16384, mS+256, sS+256);
  pool(F2,P2,128,64,64);
  conv(P2,2,F3, 128,256,64,64,1,8);
  statsk<<<1024,256,0,stream>>>(F3,4096, mS+768, sS+768);
  pool(F3,P3,256,32,32);
  conv(P3,3,f4s, 256,512,32,32,1,4);
  statsk<<<2048,256,0,stream>>>(f4s,1024, mS+1792, sS+1792);

  // ---- k-means (content r=0..3, style r=4..7) ----
  transposek<<<dim3(32,16,8),256,0,stream>>>(f4c,f4s,ptsT);
  initcentk<<<48,256,0,stream>>>(ptsT,cent);
  for (int it=0; it<10; ++it){
    assignk<<<2048,256,0,stream>>>(ptsT,cent,aPtr);
    updatek<0><<<dim3(8,16),256,0,stream>>>(ptsT,aPtr,cent,nullptr);
  }
  assignk<<<2048,256,0,stream>>>(ptsT,cent,aPtr);
  updatek<1><<<dim3(8,16),256,0,stream>>>(ptsT,aPtr,mu,counts);

  // ---- covariances + trace-scaled Newton-Schulz sqrt/invsqrt ----
  float* Yb = AR + 0;
  float* Zb = AR + 6291456ul;
  float* Y2 = AR + 12582912ul;
  float* Z2 = AR + 18874368ul;
  float* Mb = AR + 25165824ul;
  covk<<<dim3(8,8,24),256,0,stream>>>(f4c,f4s,aPtr,mu,counts,Yb);
  powk<<<24,256,0,stream>>>(Yb,sval);
  nsinitk<<<24576,256,0,stream>>>(Yb,Zb,sval);
  float* Yc=Yb; float* Zc=Zb; float* Ya=Y2; float* Za=Z2;
  for (int it=0; it<NS_ITERS; ++it){
    bmmk<0><<<dim3(8,4,24),256,0,stream>>>(Zc,Yc,Mb,512,512,512,(long long)MSZ,(long long)MSZ,(long long)MSZ,1,nullptr,nullptr);
    scalek<<<24,256,0,stream>>>(Mb,gbuf,obuf);
    bmmk<2><<<dim3(8,4,24),256,0,stream>>>(Yc,Mb,Ya,512,512,512,(long long)MSZ,(long long)MSZ,(long long)MSZ,1,gbuf,obuf);
    bmmk<1><<<dim3(8,4,24),256,0,stream>>>(Mb,Zc,Za,512,512,512,(long long)MSZ,(long long)MSZ,(long long)MSZ,1,gbuf,obuf);
    float* t1=Yc; Yc=Ya; Ya=t1;
    float* t2=Zc; Zc=Za; Za=t2;
  }
  // T[b] = sqrt(s_s/s_c) * Y_style[b] @ Z_content[b]
  make_scalesk<<<1,64,0,stream>>>(sval,scl);
  bmmk<0><<<dim3(8,4,12),256,0,stream>>>(Yc+(size_t)12*MSZ, Zc, Tmat, 512,512,512,
                                         (long long)MSZ,(long long)MSZ,(long long)MSZ,1,nullptr,scl);
  tveck<<<12,512,0,stream>>>(Tmat,mu,tvec);
  // tpts[b] = T[b] @ f[img]   (b = img*3+k)
  bmmk<0><<<dim3(16,4,12),256,0,stream>>>(Tmat, f4c, Mb, 512,1024,512,
                                          (long long)MSZ,524288ll,524288ll,3,nullptr,nullptr);
  selectk<<<8192,256,0,stream>>>(Mb,tvec,aPtr,f4c,tf);

  // ---- decode ----
  float* X1 = AR + 0;
  float* U1 = AR + 1048576ul;
  float* X2 = AR + 5242880ul;
  float* U2 = AR + 7340032ul;
  float* X3 = AR + 0;
  float* U3 = AR + 4194304ul;
  conv(tf, 4, X1, 512,256,32,32,1,4);
  up(X1,U1,256,64,64);
  conv(U1,5,X2, 256,128,64,64,1,4);
  up(X2,U2,128,128,128);
  conv(U2,6,X3, 128,64,128,128,1,8);
  up(X3,U3,64,256,256);
  conv(U3,7,dec, 64,3,256,256,0,4);

  // ---- decoded encode + stats + content loss ----
  float* mD = sm + SM_STATS_D;
  float* sD = sm + SM_STATS_D + 3840;
  conv(dec, 0, F1, 3,64,256,256,1,8);
  statsk<<<256,256,0,stream>>>(F1,65536, mD+0, sD+0);
  pool(F1,P1,64,128,128);
  conv(P1,1,F2, 64,128,128,128,1,8);
  statsk<<<512,256,0,stream>>>(F2,16384, mD+256, sD+256);
  pool(F2,P2,128,64,64);
  conv(P2,2,F3, 128,256,64,64,1,8);
  statsk<<<1024,256,0,stream>>>(F3,4096, mD+768, sD+768);
  pool(F3,P3,256,32,32);
  conv(P3,3,tf, 256,512,32,32,1,4);   // f4(dec) reuses tf buffer
  statsk<<<2048,256,0,stream>>>(tf,1024, mD+1792, sD+1792);
  clossk<<<2048,256,0,stream>>>(tf,f4c,2097152, sm+SM_CLOSS);
  finalk<<<1,256,0,stream>>>(sm,out);
}

// Round 4
// 9405.856 us; speedup vs baseline: 1.6591x; 1.0458x over previous
//
#include <hip/hip_runtime.h>
#include <cstddef>

#define NS_ITERS 12
#define MSZ 262144  // 512*512
#define PL  6291456 // 24*MSZ elements (one full split plane, in u16 elements)

typedef unsigned short u16;
typedef __attribute__((ext_vector_type(8))) short bf16x8;
typedef __attribute__((ext_vector_type(4))) float f32x4;

__device__ inline u16 bf16_rne(float x){
  unsigned u = __float_as_uint(x);
  unsigned r = u + 0x7fffu + ((u>>16)&1u);
  return (u16)(r>>16);
}
__device__ inline float bf16f(u16 h){
  return __uint_as_float(((unsigned)h)<<16);
}

// ---------------- workspace offsets (in floats) ----------------
#define OFF_F4C   0ul
#define OFF_F4S   2097152ul
#define OFF_TF    4194304ul
#define OFF_DEC   6291456ul
#define OFF_TMAT  7077888ul      // 12*512*512 fp32
#define OFF_SMALL 10223616ul     // 131072 floats of small stuff (zeroed each launch)
#define OFF_ARENA 10354688ul     // 31457280 floats reusable arena

// SMALL sub-offsets (floats)
#define SM_CENT    0
#define SM_ASSIGN  12288
#define SM_MU      20480
#define SM_COUNTS  32768
#define SM_SVAL    32800
#define SM_SCALE   32832
#define SM_TVEC    32864
#define SM_STATS_S 39008
#define SM_STATS_D 46688
#define SM_CLOSS   54368
#define SM_G       54400
#define SM_OS      54432

// ---------------- kernels ----------------

__global__ __launch_bounds__(256) void zerok(float* p, int n){
  int i = blockIdx.x*256 + threadIdx.x;
  if (i < n) p[i] = 0.f;
}

// direct 3x3 SAME conv, NCHW. 32x32 spatial tile, 256 thr (2x2 px each), COT couts/block, 8-ci chunks.
template<int COT>
__global__ __launch_bounds__(256) void conv3x3(
    const float* __restrict__ in, const float* __restrict__ wgt,
    const float* __restrict__ bias, float* __restrict__ out,
    int B, int Cin, int Cout, int H, int W, int relu)
{
  __shared__ float s_in[8][34][34];
  __shared__ float s_w[COT][8][9];
  const int tid = threadIdx.x;
  const int tx = tid & 15, ty = tid >> 4;
  const int tilesW = W >> 5;
  const int h0 = (blockIdx.x / tilesW) << 5;
  const int w0 = (blockIdx.x % tilesW) << 5;
  const int co0 = blockIdx.y * COT;
  const int b = blockIdx.z;
  float acc[COT][2][2];
  #pragma unroll
  for (int o=0;o<COT;o++){acc[o][0][0]=0.f;acc[o][0][1]=0.f;acc[o][1][0]=0.f;acc[o][1][1]=0.f;}
  const int y0 = ty*2, x0 = tx*2;
  for (int ci0 = 0; ci0 < Cin; ci0 += 8){
    const int cic = (Cin - ci0 < 8) ? (Cin - ci0) : 8;
    const int tot = cic*1156;
    for (int e = tid; e < tot; e += 256){
      int c = e / 1156; int r = e - c*1156;
      int lh = r / 34, lw = r - lh*34;
      int ih = h0 + lh - 1, iw = w0 + lw - 1;
      float v = 0.f;
      if ((unsigned)ih < (unsigned)H && (unsigned)iw < (unsigned)W)
        v = in[((size_t)(b*Cin + ci0 + c)*H + ih)*W + iw];
      s_in[c][lh][lw] = v;
    }
    const int wtot = COT*cic*9;
    for (int e = tid; e < wtot; e += 256){
      int o = e / (cic*9); int r = e - o*(cic*9);
      int c = r / 9, t = r - c*9;
      int co = co0 + o;
      float v = 0.f;
      if (co < Cout) v = wgt[(size_t)(co*Cin + ci0 + c)*9 + t];
      s_w[o][c][t] = v;
    }
    __syncthreads();
    for (int c = 0; c < cic; ++c){
      float p[4][4];
      #pragma unroll
      for (int r=0;r<4;r++)
        #pragma unroll
        for (int s=0;s<4;s++)
          p[r][s] = s_in[c][y0+r][x0+s];
      #pragma unroll
      for (int dh=0; dh<3; dh++)
        #pragma unroll
        for (int dw=0; dw<3; dw++){
          #pragma unroll
          for (int o=0;o<COT;o++){
            float wv = s_w[o][c][dh*3+dw];
            acc[o][0][0] = fmaf(p[dh  ][dw  ], wv, acc[o][0][0]);
            acc[o][0][1] = fmaf(p[dh  ][dw+1], wv, acc[o][0][1]);
            acc[o][1][0] = fmaf(p[dh+1][dw  ], wv, acc[o][1][0]);
            acc[o][1][1] = fmaf(p[dh+1][dw+1], wv, acc[o][1][1]);
          }
        }
    }
    __syncthreads();
  }
  #pragma unroll
  for (int o=0;o<COT;o++){
    int co = co0 + o;
    if (co >= Cout) continue;
    float bv = bias[co];
    #pragma unroll
    for (int r=0;r<2;r++)
      #pragma unroll
      for (int s=0;s<2;s++){
        float v = acc[o][r][s] + bv;
        if (relu) v = fmaxf(v, 0.f);
        out[((size_t)(b*Cout + co)*H + h0+y0+r)*W + w0+x0+s] = v;
      }
  }
}

__global__ __launch_bounds__(256) void pool2k(const float* __restrict__ in, float* __restrict__ out,
                                              int n, int Ho, int Wo){
  int idx = blockIdx.x*256 + threadIdx.x;
  if (idx >= n) return;
  int wo = idx % Wo; int t = idx / Wo; int ho = t % Ho; int bc = t / Ho;
  const float* p = in + ((size_t)bc*(Ho*2) + ho*2)*(size_t)(Wo*2) + (size_t)wo*2;
  out[idx] = 0.25f*(p[0] + p[1] + p[2*Wo] + p[2*Wo+1]);
}

__global__ __launch_bounds__(256) void up2k(const float* __restrict__ in, float* __restrict__ out,
                                            int n, int Ho, int Wo){
  int idx = blockIdx.x*256 + threadIdx.x;
  if (idx >= n) return;
  int wo = idx % Wo; int t = idx / Wo; int ho = t % Ho; int bc = t / Ho;
  int Hi = Ho >> 1, Wi = Wo >> 1;
  out[idx] = in[((size_t)bc*Hi + (ho>>1))*Wi + (wo>>1)];
}

// per-(b,c) spatial mean & std (ddof=0)
__global__ __launch_bounds__(256) void statsk(const float* __restrict__ x, int HW,
                                              float* __restrict__ mo, float* __restrict__ so){
  int bc = blockIdx.x, tid = threadIdx.x;
  const float* p = x + (size_t)bc*HW;
  double s = 0.0, s2 = 0.0;
  for (int i = tid; i < HW; i += 256){ double v = p[i]; s += v; s2 += v*v; }
  __shared__ double sh[256], sh2[256];
  sh[tid] = s; sh2[tid] = s2; __syncthreads();
  for (int k=128;k>0;k>>=1){ if (tid<k){ sh[tid]+=sh[tid+k]; sh2[tid]+=sh2[tid+k]; } __syncthreads(); }
  if (tid == 0){
    double m = sh[0]/HW;
    double var = sh2[0]/HW - m*m;
    if (var < 0.0) var = 0.0;
    mo[bc] = (float)m;
    so[bc] = (float)sqrt(var);
  }
}

// f4 (C-major, per image 512x1024) -> ptsT [8][1024][512]
__global__ __launch_bounds__(256) void transposek(const float* __restrict__ f4c,
                                                  const float* __restrict__ f4s,
                                                  float* __restrict__ ptsT){
  __shared__ float t[32][33];
  int r = blockIdx.z;
  const float* src = (r < 4) ? (f4c + (size_t)r*524288) : (f4s + (size_t)(r-4)*524288);
  int n0 = blockIdx.x*32, c0 = blockIdx.y*32;
  int lx = threadIdx.x & 31, ly = threadIdx.x >> 5;
  for (int j=0;j<32;j+=8)
    t[ly+j][lx] = src[(size_t)(c0+ly+j)*1024 + n0+lx];
  __syncthreads();
  for (int j=0;j<32;j+=8)
    ptsT[((size_t)r*1024 + n0+ly+j)*512 + c0+lx] = t[lx][ly+j];
}

__global__ __launch_bounds__(256) void initcentk(const float* __restrict__ ptsT, float* __restrict__ cent){
  int i = blockIdx.x*256 + threadIdx.x;
  if (i >= 12288) return;
  int c = i & 511; int k = (i >> 9) % 3; int r = i / 1536;
  cent[i] = ptsT[((size_t)r*1024 + k)*512 + c];
}

// one wave per point; first-min argmin (matches jnp.argmin)
__global__ __launch_bounds__(256) void assignk(const float* __restrict__ ptsT,
                                               const float* __restrict__ cent, int* __restrict__ a){
  int gp = blockIdx.x*4 + (threadIdx.x >> 6);
  int lane = threadIdx.x & 63;
  int r = gp >> 10;
  const float* p = ptsT + (size_t)gp*512;
  const float* ce = cent + r*1536;
  float d0=0.f,d1=0.f,d2=0.f;
  #pragma unroll
  for (int i=0;i<8;i++){
    int c = lane + i*64;
    float v = p[c];
    float e0 = v - ce[c], e1 = v - ce[512+c], e2 = v - ce[1024+c];
    d0 = fmaf(e0,e0,d0); d1 = fmaf(e1,e1,d1); d2 = fmaf(e2,e2,d2);
  }
  #pragma unroll
  for (int off=32; off>0; off>>=1){
    d0 += __shfl_down(d0, off, 64);
    d1 += __shfl_down(d1, off, 64);
    d2 += __shfl_down(d2, off, 64);
  }
  if (lane == 0){
    int bi = 0; float bd = d0;
    if (d1 < bd){ bd = d1; bi = 1; }
    if (d2 < bd){ bd = d2; bi = 2; }
    a[gp] = bi;
  }
}

// parallel centroid update: grid (r=8, cc=16), 256 thr
template<int WRITE>
__global__ __launch_bounds__(256) void updatek(const float* __restrict__ ptsT,
                                               const int* __restrict__ a,
                                               float* __restrict__ dst,
                                               float* __restrict__ counts){
  int r = blockIdx.x, cc = blockIdx.y;
  int tid = threadIdx.x;
  int lane = tid & 31, p = tid >> 5;
  int c = cc*32 + lane;
  __shared__ int sa[1024];
  __shared__ int scnt[3];
  if (tid < 3) scnt[tid] = 0;
  for (int i = tid; i < 1024; i += 256) sa[i] = a[r*1024 + i];
  __syncthreads();
  {
    int l0=0,l1=0,l2=0;
    #pragma unroll
    for (int i=tid*4;i<tid*4+4;i++){ int an=sa[i]; l0+=(an==0); l1+=(an==1); l2+=(an==2); }
    if (l0) atomicAdd(&scnt[0], l0);
    if (l1) atomicAdd(&scnt[1], l1);
    if (l2) atomicAdd(&scnt[2], l2);
  }
  const float* base = ptsT + (size_t)r*524288;
  float s0=0.f,s1=0.f,s2=0.f;
  for (int n = p*128; n < p*128+128; ++n){
    float v = base[(size_t)n*512 + c];
    int an = sa[n];
    s0 += (an==0) ? v : 0.f;
    s1 += (an==1) ? v : 0.f;
    s2 += (an==2) ? v : 0.f;
  }
  __shared__ float red[8][3][32];
  red[p][0][lane]=s0; red[p][1][lane]=s1; red[p][2][lane]=s2;
  __syncthreads();
  if (p == 0){
    float t0=0.f,t1=0.f,t2=0.f;
    #pragma unroll
    for (int q=0;q<8;q++){ t0+=red[q][0][lane]; t1+=red[q][1][lane]; t2+=red[q][2][lane]; }
    float n0 = (float)scnt[0] + 1e-6f, n1 = (float)scnt[1] + 1e-6f, n2 = (float)scnt[2] + 1e-6f;
    if (WRITE == 0){
      dst[r*1536 + c]        = t0/n0;
      dst[r*1536 + 512 + c]  = t1/n1;
      dst[r*1536 + 1024 + c] = t2/n2;
    } else {
      int cs = r >> 2, img = r & 3;
      int i0 = cs*12 + img*3;
      dst[(size_t)(i0+0)*512 + c] = t0/n0;
      dst[(size_t)(i0+1)*512 + c] = t1/n1;
      dst[(size_t)(i0+2)*512 + c] = t2/n2;
      if (cc == 0 && lane == 0){
        counts[i0]   = (float)scnt[0];
        counts[i0+1] = (float)scnt[1];
        counts[i0+2] = (float)scnt[2];
      }
    }
  }
}

// 24 masked covariances: Y[z] = cov + 0.1 I   (z = cs*12 + img*3 + k)
__global__ __launch_bounds__(256) void covk(const float* __restrict__ f4c, const float* __restrict__ f4s,
        const int* __restrict__ a, const float* __restrict__ mu,
        const float* __restrict__ counts, float* __restrict__ Y){
  int z = blockIdx.z;
  int cs = z / 12; int rem = z - cs*12; int img = rem / 3; int k = rem - img*3;
  const float* pts = (cs ? f4s : f4c) + (size_t)img*524288;
  const int* an = a + (cs*4 + img)*1024;
  const float* m = mu + (size_t)z*512;
  float nc = counts[z] + 1e-6f;
  int I = blockIdx.y*64, J = blockIdx.x*64;
  __shared__ float SI[32][65], SJ[32][65];
  int tid = threadIdx.x;
  int tx = tid & 15, ty = tid >> 4;
  float acc[4][4] = {};
  for (int n0 = 0; n0 < 1024; n0 += 32){
    for (int e = tid; e < 2048; e += 256){
      int i = e >> 5, nn = e & 31;
      int n = n0 + nn;
      float msk = (an[n] == k) ? 1.f : 0.f;
      SI[nn][i] = msk * (pts[(size_t)(I+i)*1024 + n] - m[I+i]);
    }
    for (int e = tid; e < 2048; e += 256){
      int j = e >> 5, nn = e & 31;
      int n = n0 + nn;
      float msk = (an[n] == k) ? 1.f : 0.f;
      SJ[nn][j] = msk * (pts[(size_t)(J+j)*1024 + n] - m[J+j]);
    }
    __syncthreads();
    #pragma unroll 8
    for (int nn=0; nn<32; nn++){
      float ri[4], rj[4];
      #pragma unroll
      for (int q=0;q<4;q++){ ri[q] = SI[nn][ty*4+q]; rj[q] = SJ[nn][tx*4+q]; }
      #pragma unroll
      for (int qi=0;qi<4;qi++)
        #pragma unroll
        for (int qj=0;qj<4;qj++)
          acc[qi][qj] = fmaf(ri[qi], rj[qj], acc[qi][qj]);
    }
    __syncthreads();
  }
  float inv = 1.f/nc;
  #pragma unroll
  for (int qi=0;qi<4;qi++){
    int gi = I + ty*4 + qi;
    #pragma unroll
    for (int qj=0;qj<4;qj++){
      int gj = J + tx*4 + qj;
      Y[(size_t)z*MSZ + (size_t)gi*512 + gj] = acc[qi][qj]*inv + ((gi==gj)?0.1f:0.f);
    }
  }
}

// power iteration for lambda_max
__global__ __launch_bounds__(256) void powk(const float* __restrict__ Y, float* __restrict__ sval){
  int z = blockIdx.x, tid = threadIdx.x;
  const float* M = Y + (size_t)z*MSZ;
  __shared__ float v[512];
  __shared__ float red[256];
  __shared__ float nrmsh;
  v[tid] = 1.f; v[tid+256] = 1.f;
  __syncthreads();
  float lastn = 0.1f;
  for (int it=0; it<10; ++it){
    float y0=0.f, y1=0.f;
    for (int c=0;c<512;c++){
      float vc = v[c];
      y0 = fmaf(M[(size_t)c*512 + tid      ], vc, y0);
      y1 = fmaf(M[(size_t)c*512 + tid + 256], vc, y1);
    }
    red[tid] = y0*y0 + y1*y1;
    __syncthreads();
    for (int s=128;s>0;s>>=1){ if (tid<s) red[tid]+=red[tid+s]; __syncthreads(); }
    if (tid==0) nrmsh = sqrtf(red[0]) + 1e-30f;
    __syncthreads();
    float nrm = nrmsh;
    v[tid] = y0/nrm; v[tid+256] = y1/nrm;
    lastn = nrm;
    __syncthreads();
  }
  if (tid==0) sval[z] = lastn*1.05f + 1e-12f;
}

// init split planes: Y = Ycov/s (hi+lo bf16), Z = I
__global__ __launch_bounds__(256) void nsinitk(const float* __restrict__ Ycov, const float* __restrict__ sval,
                                               u16* __restrict__ Yh, u16* __restrict__ Yl,
                                               u16* __restrict__ Zh, u16* __restrict__ Zl){
  size_t idx = (size_t)blockIdx.x*256 + threadIdx.x;
  if (idx >= (size_t)PL) return;
  int z = (int)(idx >> 18);
  int rc = (int)(idx & (MSZ-1));
  int rr = rc >> 9, cc = rc & 511;
  float y = Ycov[idx] / sval[z];
  u16 h = bf16_rne(y);
  Yh[idx] = h;
  Yl[idx] = bf16_rne(y - bf16f(h));
  Zh[idx] = (rr==cc) ? (u16)0x3F80 : (u16)0;
  Zl[idx] = 0;
}

// trace-scaled NS factors from split M: g = min(512/tr, 2.7); os = sqrt(g)/2
__global__ __launch_bounds__(256) void scalek(const u16* __restrict__ Mh, const u16* __restrict__ Ml,
                                              float* __restrict__ g, float* __restrict__ os){
  int z = blockIdx.x, tid = threadIdx.x;
  const u16* H = Mh + (size_t)z*MSZ;
  const u16* L = Ml + (size_t)z*MSZ;
  float s = bf16f(H[(size_t)tid*513]) + bf16f(L[(size_t)tid*513])
          + bf16f(H[(size_t)(tid+256)*513]) + bf16f(L[(size_t)(tid+256)*513]);
  __shared__ float sh[256];
  sh[tid] = s; __syncthreads();
  for (int k=128;k>0;k>>=1){ if (tid<k) sh[tid]+=sh[tid+k]; __syncthreads(); }
  if (tid==0){
    float tr = fmaxf(sh[0], 1e-6f);
    float g2 = fminf(512.f/tr, 2.7f);
    g[z] = g2;
    os[z] = 0.5f*sqrtf(g2);
  }
}

// ---- split-bf16 MFMA batched GEMM, general B (staged transposed in LDS) ----
// 512x512x512 per batch, 128x128 block tile, 4 waves of 64x64, mfma_f32_16x16x32_bf16.
// MODE 0: C(split) = A@B
// MODE 1: C(split) = os*(3*D - g*(A@B))     (the Newton-Schulz update)
// MODE 2: Cf(f32)  = osc*(A@B)
template<int MODE>
__global__ __launch_bounds__(256) void bmms(
    const u16* __restrict__ Ah, const u16* __restrict__ Al,
    const u16* __restrict__ Bh, const u16* __restrict__ Bl,
    const u16* __restrict__ Dh, const u16* __restrict__ Dl,
    u16* __restrict__ Ch, u16* __restrict__ Cl,
    float* __restrict__ Cf,
    const float* __restrict__ gam, const float* __restrict__ osc,
    int aoff)
{
  const int z = blockIdx.z;
  const u16* Abh = Ah + (size_t)(z+aoff)*MSZ;
  const u16* Abl = Al + (size_t)(z+aoff)*MSZ;
  const u16* Bbh = Bh + (size_t)z*MSZ;
  const u16* Bbl = Bl + (size_t)z*MSZ;
  const int m0 = blockIdx.y*128, n0 = blockIdx.x*128;
  const int tid = threadIdx.x;

  // A tiles row-major [m][k] (pad 40); B tiles stored TRANSPOSED [n][k] (pad 40)
  __shared__ __align__(16) u16 sAh[128*40], sAl[128*40];
  __shared__ __align__(16) u16 sBh[128*40], sBl[128*40];

  // A staging: rows ra, ra+64 ; k-group qa
  const int ra = tid >> 2, qa = tid & 3;
  // B staging: k-rows kb, kb+16 ; col-group gb
  const int kb = tid >> 4, gb = tid & 15;

  const int wid = tid >> 6, lane = tid & 63;
  const int wm = wid >> 1, wn = wid & 1;
  const int quad = lane >> 4, ln = lane & 15;

  f32x4 acc[4][4];
  #pragma unroll
  for (int i=0;i<4;i++)
    #pragma unroll
    for (int j=0;j<4;j++)
      #pragma unroll
      for (int e=0;e<4;e++) acc[i][j][e] = 0.f;

  for (int k0 = 0; k0 < 512; k0 += 32){
    // ---- stage A (row-major, contiguous vec8) ----
    *(bf16x8*)&sAh[ra*40 + qa*8]      = *(const bf16x8*)&Abh[(size_t)(m0+ra)*512    + k0 + qa*8];
    *(bf16x8*)&sAl[ra*40 + qa*8]      = *(const bf16x8*)&Abl[(size_t)(m0+ra)*512    + k0 + qa*8];
    *(bf16x8*)&sAh[(ra+64)*40 + qa*8] = *(const bf16x8*)&Abh[(size_t)(m0+ra+64)*512 + k0 + qa*8];
    *(bf16x8*)&sAl[(ra+64)*40 + qa*8] = *(const bf16x8*)&Abl[(size_t)(m0+ra+64)*512 + k0 + qa*8];
    // ---- stage B transposed: read B row k (contiguous), scatter to [n][k] ----
    {
      bf16x8 vh = *(const bf16x8*)&Bbh[(size_t)(k0+kb)*512 + n0 + gb*8];
      bf16x8 vl = *(const bf16x8*)&Bbl[(size_t)(k0+kb)*512 + n0 + gb*8];
      #pragma unroll
      for (int j=0;j<8;j++){
        sBh[(gb*8+j)*40 + kb] = (u16)vh[j];
        sBl[(gb*8+j)*40 + kb] = (u16)vl[j];
      }
      vh = *(const bf16x8*)&Bbh[(size_t)(k0+kb+16)*512 + n0 + gb*8];
      vl = *(const bf16x8*)&Bbl[(size_t)(k0+kb+16)*512 + n0 + gb*8];
      #pragma unroll
      for (int j=0;j<8;j++){
        sBh[(gb*8+j)*40 + kb+16] = (u16)vh[j];
        sBl[(gb*8+j)*40 + kb+16] = (u16)vl[j];
      }
    }
    __syncthreads();

    bf16x8 ah[4], al[4], bh[4], bl[4];
    #pragma unroll
    for (int t=0;t<4;t++){
      const int moA = ((wm*4+t)*16 + ln)*40 + quad*8;
      const int moB = ((wn*4+t)*16 + ln)*40 + quad*8;
      ah[t] = *(const bf16x8*)&sAh[moA];
      al[t] = *(const bf16x8*)&sAl[moA];
      bh[t] = *(const bf16x8*)&sBh[moB];
      bl[t] = *(const bf16x8*)&sBl[moB];
    }
    #pragma unroll
    for (int mi=0;mi<4;mi++)
      #pragma unroll
      for (int ni=0;ni<4;ni++){
        acc[mi][ni] = __builtin_amdgcn_mfma_f32_16x16x32_bf16(ah[mi], bh[ni], acc[mi][ni], 0, 0, 0);
        acc[mi][ni] = __builtin_amdgcn_mfma_f32_16x16x32_bf16(ah[mi], bl[ni], acc[mi][ni], 0, 0, 0);
        acc[mi][ni] = __builtin_amdgcn_mfma_f32_16x16x32_bf16(al[mi], bh[ni], acc[mi][ni], 0, 0, 0);
      }
    __syncthreads();
  }

  float alpha = 1.f, beta = 0.f;
  if constexpr (MODE==1){ float gz = gam[z], oz = osc[z]; alpha = -gz*oz; beta = 3.f*oz; }
  if constexpr (MODE==2){ alpha = osc[z]; }

  #pragma unroll
  for (int mi=0;mi<4;mi++){
    const int mbase = m0 + (wm*4+mi)*16 + quad*4;
    #pragma unroll
    for (int ni=0;ni<4;ni++){
      const int n = n0 + (wn*4+ni)*16 + ln;
      #pragma unroll
      for (int rg=0;rg<4;rg++){
        const int m = mbase + rg;
        const size_t off = (size_t)z*MSZ + (size_t)m*512 + n;
        float v = alpha*acc[mi][ni][rg];
        if constexpr (MODE==1)
          v += beta*(bf16f(Dh[off]) + bf16f(Dl[off]));
        if constexpr (MODE==2){
          Cf[off] = v;
        } else {
          u16 h = bf16_rne(v);
          Ch[off] = h;
          Cl[off] = bf16_rne(v - bf16f(h));
        }
      }
    }
  }
}

// batched fp32 GEMM (kept for tpts = T @ f, non-symmetric operands)
template<int TRANS>
__global__ __launch_bounds__(256) void bmmk(const float* __restrict__ A, const float* __restrict__ B,
        float* __restrict__ C, int M, int N, int K,
        long long sA, long long sB, long long sC, int bdiv,
        const float* __restrict__ gam, const float* __restrict__ osc)
{
  int bz = blockIdx.z;
  const float* Ab = A + (size_t)bz*sA;
  const float* Bb = B + (size_t)(bz/bdiv)*sB;
  float* Cb = C + (size_t)bz*sC;
  const float g = (TRANS != 0 && gam) ? gam[bz] : 1.0f;
  const int m0 = blockIdx.y << 7, n0 = blockIdx.x << 6;
  const int tid = threadIdx.x;
  const int trow = tid >> 4;
  const int tcol = tid & 15;
  __shared__ __align__(16) float As[16][132];
  __shared__ __align__(16) float Bs[16][68];
  float acc[8][4] = {};
  for (int k0 = 0; k0 < K; k0 += 16){
    #pragma unroll
    for (int l=0;l<2;l++){
      int e = tid + l*256;
      int m = e >> 2;
      int kq = (e & 3) << 2;
      float4 v4 = *(const float4*)(Ab + (size_t)(m0+m)*K + k0 + kq);
      float vv[4] = {v4.x, v4.y, v4.z, v4.w};
      #pragma unroll
      for (int j=0;j<4;j++){
        float v = vv[j];
        if (TRANS==1) v = 3.0f*(((k0+kq+j)==(m0+m)) ? 1.f : 0.f) - g*v;
        As[kq+j][m] = v;
      }
    }
    {
      int kk = tid >> 4;
      int nq = (tid & 15) << 2;
      float4 v4 = *(const float4*)(Bb + (size_t)(k0+kk)*N + n0 + nq);
      float vv[4] = {v4.x, v4.y, v4.z, v4.w};
      #pragma unroll
      for (int j=0;j<4;j++){
        if (TRANS==2) vv[j] = 3.0f*(((k0+kk)==(n0+nq+j)) ? 1.f : 0.f) - g*vv[j];
      }
      *(float4*)(&Bs[kk][nq]) = make_float4(vv[0],vv[1],vv[2],vv[3]);
    }
    __syncthreads();
    #pragma unroll
    for (int kk=0;kk<16;kk++){
      float a8[8];
      *(float4*)(a8)     = *(const float4*)(&As[kk][trow*8]);
      *(float4*)(a8 + 4) = *(const float4*)(&As[kk][trow*8 + 4]);
      float4 b4 = *(const float4*)(&Bs[kk][tcol*4]);
      float bb[4] = {b4.x, b4.y, b4.z, b4.w};
      #pragma unroll
      for (int i=0;i<8;i++)
        #pragma unroll
        for (int j=0;j<4;j++)
          acc[i][j] = fmaf(a8[i], bb[j], acc[i][j]);
    }
    __syncthreads();
  }
  const float sc = osc ? osc[bz] : 1.0f;
  #pragma unroll
  for (int i=0;i<8;i++){
    int m = m0 + trow*8 + i;
    float4 o = make_float4(acc[i][0]*sc, acc[i][1]*sc, acc[i][2]*sc, acc[i][3]*sc);
    *(float4*)(Cb + (size_t)m*N + n0 + tcol*4) = o;
  }
}

__global__ void make_scalesk(const float* __restrict__ sval, float* __restrict__ scl){
  int i = threadIdx.x;
  if (i < 12) scl[i] = sqrtf(sval[12+i] / sval[i]);
}

// tvec[b] = mu_s[b] - T[b] @ mu_c[b]
__global__ __launch_bounds__(512) void tveck(const float* __restrict__ Tmat,
                                             const float* __restrict__ mu, float* __restrict__ tvec){
  int b = blockIdx.x; int c = threadIdx.x;
  __shared__ float mc[512];
  mc[c] = mu[(size_t)b*512 + c];
  __syncthreads();
  const float* Trow = Tmat + ((size_t)b*512 + c)*512;
  float s = 0.f;
  for (int d=0; d<512; d++) s = fmaf(Trow[d], mc[d], s);
  tvec[b*512 + c] = mu[(size_t)(12+b)*512 + c] - s;
}

__global__ __launch_bounds__(256) void selectk(const float* __restrict__ tpts, const float* __restrict__ tvec,
        const int* __restrict__ a, const float* __restrict__ f4c, float* __restrict__ tf){
  size_t idx = (size_t)blockIdx.x*256 + threadIdx.x;
  if (idx >= 2097152ul) return;
  int n = (int)(idx & 1023);
  int c = (int)((idx >> 10) & 511);
  int img = (int)(idx >> 19);
  int k = a[img*1024 + n];
  int b = img*3 + k;
  float v = tpts[((size_t)b*512 + c)*1024 + n] + tvec[b*512 + c];
  tf[idx] = 0.6f*v + 0.4f*f4c[idx];
}

__global__ __launch_bounds__(256) void clossk(const float* __restrict__ x, const float* __restrict__ y,
                                              int n, float* __restrict__ acc){
  int tid = threadIdx.x;
  float s = 0.f;
  for (size_t i = (size_t)blockIdx.x*256 + tid; i < (size_t)n; i += (size_t)gridDim.x*256){
    float d = x[i] - y[i]; s = fmaf(d, d, s);
  }
  __shared__ float sh[256];
  sh[tid] = s; __syncthreads();
  for (int k=128;k>0;k>>=1){ if (tid<k) sh[tid]+=sh[tid+k]; __syncthreads(); }
  if (tid==0) atomicAdd(acc, sh[0]);
}

__global__ __launch_bounds__(256) void finalk(const float* __restrict__ sm, float* __restrict__ out){
  int tid = threadIdx.x;
  const int cnts[4] = {256,512,1024,2048};
  const int offs[4] = {0,256,768,1792};
  const float* mS = sm + SM_STATS_S;
  const float* sS = sm + SM_STATS_S + 3840;
  const float* mD = sm + SM_STATS_D;
  const float* sD = sm + SM_STATS_D + 3840;
  double sl = 0.0;
  for (int L=0; L<4; ++L){
    int cnt = cnts[L], off = offs[L];
    double inv = 1.0/cnt;
    for (int i=tid; i<cnt; i+=256){
      double dm = (double)mD[off+i] - (double)mS[off+i];
      double ds = (double)sD[off+i] - (double)sS[off+i];
      sl += (dm*dm + ds*ds)*inv;
    }
  }
  __shared__ double sh[256];
  sh[tid] = sl; __syncthreads();
  for (int k=128;k>0;k>>=1){ if (tid<k) sh[tid]+=sh[tid+k]; __syncthreads(); }
  if (tid==0){
    double closs = (double)sm[SM_CLOSS] / 2097152.0;
    out[0] = (float)(closs + 0.01*sh[0]);
  }
}

// ---------------- host ----------------

extern "C" void kernel_launch(void* const* d_in, const int* in_sizes, int n_in,
                              void* d_out, int out_size, void* d_ws, size_t ws_size,
                              hipStream_t stream)
{
  const float* content = (const float*)d_in[0];
  const float* style   = (const float*)d_in[1];
  const float* Wm[8]; const float* Bm[8];
  for (int i=0;i<8;i++){ Wm[i] = (const float*)d_in[2+2*i]; Bm[i] = (const float*)d_in[3+2*i]; }
  float* out = (float*)d_out;
  float* ws = (float*)d_ws;

  float* f4c  = ws + OFF_F4C;
  float* f4s  = ws + OFF_F4S;
  float* tf   = ws + OFF_TF;
  float* dec  = ws + OFF_DEC;
  float* Tmat = ws + OFF_TMAT;
  float* sm   = ws + OFF_SMALL;
  float* AR   = ws + OFF_ARENA;
  int*   aPtr = (int*)(sm + SM_ASSIGN);
  float* cent = sm + SM_CENT;
  float* mu   = sm + SM_MU;
  float* counts = sm + SM_COUNTS;
  float* sval = sm + SM_SVAL;
  float* scl  = sm + SM_SCALE;
  float* tvec = sm + SM_TVEC;
  float* gbuf = sm + SM_G;
  float* obuf = sm + SM_OS;

  // NS split planes (u16), each 24*MSZ elements = 3145728 float-slots
  float* Ycov = AR;                       // fp32, dead after nsinitk
  u16* Mh  = (u16*)(AR);                  // reuses Ycov region
  u16* Ml  = (u16*)(AR + 3145728ul);
  u16* Yh  = (u16*)(AR + 6291456ul);
  u16* Yl  = (u16*)(AR + 9437184ul);
  u16* Zh  = (u16*)(AR + 12582912ul);
  u16* Zl  = (u16*)(AR + 15728640ul);
  u16* Y2h = (u16*)(AR + 18874368ul);
  u16* Y2l = (u16*)(AR + 22020096ul);
  u16* Z2h = (u16*)(AR + 25165824ul);
  u16* Z2l = (u16*)(AR + 28311552ul);
  float* ptsT = AR + 25165824ul;   // dead before Z2 planes are first written

  zerok<<<512,256,0,stream>>>(sm, 131072);

  auto conv = [&](const float* inp, int li, float* outp, int Ci,int Co,int H,int Wd,int relu,int cot){
    dim3 g((H>>5)*(Wd>>5), (Co + cot - 1)/cot, 4);
    if (cot==8) conv3x3<8><<<g,256,0,stream>>>(inp,Wm[li],Bm[li],outp,4,Ci,Co,H,Wd,relu);
    else        conv3x3<4><<<g,256,0,stream>>>(inp,Wm[li],Bm[li],outp,4,Ci,Co,H,Wd,relu);
  };
  auto pool = [&](const float* inp, float* outp, int C,int Ho,int Wo){
    int n = 4*C*Ho*Wo;
    pool2k<<<(n+255)/256,256,0,stream>>>(inp,outp,n,Ho,Wo);
  };
  auto up = [&](const float* inp, float* outp, int C,int Ho,int Wo){
    int n = 4*C*Ho*Wo;
    up2k<<<(n+255)/256,256,0,stream>>>(inp,outp,n,Ho,Wo);
  };

  // encode scratch (arena)
  float* F1 = AR + 0;
  float* P1 = AR + 16777216ul;
  float* F2 = AR + 0;
  float* P2 = AR + 8388608ul;
  float* F3 = AR + 10485760ul;
  float* P3 = AR + 0;

  // ---- content encode ----
  conv(content, 0, F1, 3,64,256,256,1,8);
  pool(F1,P1,64,128,128);
  conv(P1,1,F2, 64,128,128,128,1,8);
  pool(F2,P2,128,64,64);
  conv(P2,2,F3, 128,256,64,64,1,8);
  pool(F3,P3,256,32,32);
  conv(P3,3,f4c, 256,512,32,32,1,4);

  // ---- style encode + stats ----
  float* mS = sm + SM_STATS_S;
  float* sS = sm + SM_STATS_S + 3840;
  conv(style, 0, F1, 3,64,256,256,1,8);
  statsk<<<256,256,0,stream>>>(F1,65536, mS+0, sS+0);
  pool(F1,P1,64,128,128);
  conv(P1,1,F2, 64,128,128,128,1,8);
  statsk<<<512,256,0,stream>>>(F2,16384, mS+256, sS+256);
  pool(F2,P2,128,64,64);
  conv(P2,2,F3, 128,256,64,64,1,8);
  statsk<<<1024,256,0,stream>>>(F3,4096, mS+768, sS+768);
  pool(F3,P3,256,32,32);
  conv(P3,3,f4s, 256,512,32,32,1,4);
  statsk<<<2048,256,0,stream>>>(f4s,1024, mS+1792, sS+1792);

  // ---- k-means (content r=0..3, style r=4..7) ----
  transposek<<<dim3(32,16,8),256,0,stream>>>(f4c,f4s,ptsT);
  initcentk<<<48,256,0,stream>>>(ptsT,cent);
  for (int it=0; it<10; ++it){
    assignk<<<2048,256,0,stream>>>(ptsT,cent,aPtr);
    updatek<0><<<dim3(8,16),256,0,stream>>>(ptsT,aPtr,cent,nullptr);
  }
  assignk<<<2048,256,0,stream>>>(ptsT,cent,aPtr);
  updatek<1><<<dim3(8,16),256,0,stream>>>(ptsT,aPtr,mu,counts);

  // ---- covariances + split-bf16 MFMA Newton-Schulz ----
  covk<<<dim3(8,8,24),256,0,stream>>>(f4c,f4s,aPtr,mu,counts,Ycov);
  powk<<<24,256,0,stream>>>(Ycov,sval);
  nsinitk<<<24576,256,0,stream>>>(Ycov,sval,Yh,Yl,Zh,Zl);
  u16 *Ych=Yh,*Ycl=Yl,*Zch=Zh,*Zcl=Zl,*Yah=Y2h,*Yal=Y2l,*Zah=Z2h,*Zal=Z2l;
  for (int it=0; it<NS_ITERS; ++it){
    bmms<0><<<dim3(4,4,24),256,0,stream>>>(Zch,Zcl,Ych,Ycl,nullptr,nullptr,Mh,Ml,nullptr,nullptr,nullptr,0);
    scalek<<<24,256,0,stream>>>(Mh,Ml,gbuf,obuf);
    bmms<1><<<dim3(4,4,24),256,0,stream>>>(Ych,Ycl,Mh,Ml,Ych,Ycl,Yah,Yal,nullptr,gbuf,obuf,0);
    bmms<1><<<dim3(4,4,24),256,0,stream>>>(Mh,Ml,Zch,Zcl,Zch,Zcl,Zah,Zal,nullptr,gbuf,obuf,0);
    u16* t;
    t=Ych;Ych=Yah;Yah=t; t=Ycl;Ycl=Yal;Yal=t;
    t=Zch;Zch=Zah;Zah=t; t=Zcl;Zcl=Zal;Zal=t;
  }
  // T[b] = sqrt(s_s/s_c) * Y_style[b] @ Z_content[b]  (fp32 out)
  make_scalesk<<<1,64,0,stream>>>(sval,scl);
  bmms<2><<<dim3(4,4,12),256,0,stream>>>(Ych,Ycl,Zch,Zcl,nullptr,nullptr,nullptr,nullptr,Tmat,nullptr,scl,12);
  tveck<<<12,512,0,stream>>>(Tmat,mu,tvec);
  // tpts[b] = T[b] @ f[img]   (b = img*3+k), fp32
  float* Mb = AR + 0;
  bmmk<0><<<dim3(16,4,12),256,0,stream>>>(Tmat, f4c, Mb, 512,1024,512,
                                          (long long)MSZ,524288ll,524288ll,3,nullptr,nullptr);
  selectk<<<8192,256,0,stream>>>(Mb,tvec,aPtr,f4c,tf);

  // ---- decode ----
  float* X1 = AR + 0;
  float* U1 = AR + 1048576ul;
  float* X2 = AR + 5242880ul;
  float* U2 = AR + 7340032ul;
  float* X3 = AR + 0;
  float* U3 = AR + 4194304ul;
  conv(tf, 4, X1, 512,256,32,32,1,4);
  up(X1,U1,256,64,64);
  conv(U1,5,X2, 256,128,64,64,1,4);
  up(X2,U2,128,128,128);
  conv(U2,6,X3, 128,64,128,128,1,8);
  up(X3,U3,64,256,256);
  conv(U3,7,dec, 64,3,256,256,0,4);

  // ---- decoded encode + stats + content loss ----
  float* mD = sm + SM_STATS_D;
  float* sD = sm + SM_STATS_D + 3840;
  conv(dec, 0, F1, 3,64,256,256,1,8);
  statsk<<<256,256,0,stream>>>(F1,65536, mD+0, sD+0);
  pool(F1,P1,64,128,128);
  conv(P1,1,F2, 64,128,128,128,1,8);
  statsk<<<512,256,0,stream>>>(F2,16384, mD+256, sD+256);
  pool(F2,P2,128,64,64);
  conv(P2,2,F3, 128,256,64,64,1,8);
  statsk<<<1024,256,0,stream>>>(F3,4096, mD+768, sD+768);
  pool(F3,P3,256,32,32);
  conv(P3,3,tf, 256,512,32,32,1,4);   // f4(dec) reuses tf buffer
  statsk<<<2048,256,0,stream>>>(tf,1024, mD+1792, sD+1792);
  clossk<<<2048,256,0,stream>>>(tf,f4c,2097152, sm+SM_CLOSS);
  finalk<<<1,256,0,stream>>>(sm,out);
}

// Round 5
// 6451.785 us; speedup vs baseline: 2.4188x; 1.4579x over previous
//
#include <hip/hip_runtime.h>
#include <cstddef>

#define NS_ITERS 12
#define MSZ 262144  // 512*512
#define PL  6291456 // 24*MSZ elements (one full split plane, in u16 elements)

typedef unsigned short u16;
typedef __attribute__((ext_vector_type(8))) short bf16x8;
typedef __attribute__((ext_vector_type(4))) float f32x4;

__device__ inline u16 bf16_rne(float x){
  unsigned u = __float_as_uint(x);
  unsigned r = u + 0x7fffu + ((u>>16)&1u);
  return (u16)(r>>16);
}
__device__ inline float bf16f(u16 h){
  return __uint_as_float(((unsigned)h)<<16);
}

// ---------------- workspace offsets (in floats) ----------------
#define OFF_F4C   0ul
#define OFF_F4S   2097152ul
#define OFF_TF    4194304ul
#define OFF_DEC   6291456ul
#define OFF_TMAT  7077888ul      // 12*512*512 fp32
#define OFF_SMALL 10223616ul     // 131072 floats of small stuff (zeroed each launch)
#define OFF_ARENA 10354688ul     // 31457280 floats reusable arena

// SMALL sub-offsets (floats)
#define SM_CENT    0
#define SM_ASSIGN  12288
#define SM_MU      20480
#define SM_COUNTS  32768
#define SM_SVAL    32800
#define SM_SCALE   32832
#define SM_TVEC    32864
#define SM_STATS_S 39008
#define SM_STATS_D 46688
#define SM_CLOSS   54368
#define SM_G       54400
#define SM_OS      54432

// ---------------- kernels ----------------

__global__ __launch_bounds__(256) void zerok(float* p, int n){
  int i = blockIdx.x*256 + threadIdx.x;
  if (i < n) p[i] = 0.f;
}

// direct 3x3 SAME conv (kept for e1: Cin=3, and d4: Cout=3)
template<int COT>
__global__ __launch_bounds__(256) void conv3x3(
    const float* __restrict__ in, const float* __restrict__ wgt,
    const float* __restrict__ bias, float* __restrict__ out,
    int B, int Cin, int Cout, int H, int W, int relu)
{
  __shared__ float s_in[8][34][34];
  __shared__ float s_w[COT][8][9];
  const int tid = threadIdx.x;
  const int tx = tid & 15, ty = tid >> 4;
  const int tilesW = W >> 5;
  const int h0 = (blockIdx.x / tilesW) << 5;
  const int w0 = (blockIdx.x % tilesW) << 5;
  const int co0 = blockIdx.y * COT;
  const int b = blockIdx.z;
  float acc[COT][2][2];
  #pragma unroll
  for (int o=0;o<COT;o++){acc[o][0][0]=0.f;acc[o][0][1]=0.f;acc[o][1][0]=0.f;acc[o][1][1]=0.f;}
  const int y0 = ty*2, x0 = tx*2;
  for (int ci0 = 0; ci0 < Cin; ci0 += 8){
    const int cic = (Cin - ci0 < 8) ? (Cin - ci0) : 8;
    const int tot = cic*1156;
    for (int e = tid; e < tot; e += 256){
      int c = e / 1156; int r = e - c*1156;
      int lh = r / 34, lw = r - lh*34;
      int ih = h0 + lh - 1, iw = w0 + lw - 1;
      float v = 0.f;
      if ((unsigned)ih < (unsigned)H && (unsigned)iw < (unsigned)W)
        v = in[((size_t)(b*Cin + ci0 + c)*H + ih)*W + iw];
      s_in[c][lh][lw] = v;
    }
    const int wtot = COT*cic*9;
    for (int e = tid; e < wtot; e += 256){
      int o = e / (cic*9); int r = e - o*(cic*9);
      int c = r / 9, t = r - c*9;
      int co = co0 + o;
      float v = 0.f;
      if (co < Cout) v = wgt[(size_t)(co*Cin + ci0 + c)*9 + t];
      s_w[o][c][t] = v;
    }
    __syncthreads();
    for (int c = 0; c < cic; ++c){
      float p[4][4];
      #pragma unroll
      for (int r=0;r<4;r++)
        #pragma unroll
        for (int s=0;s<4;s++)
          p[r][s] = s_in[c][y0+r][x0+s];
      #pragma unroll
      for (int dh=0; dh<3; dh++)
        #pragma unroll
        for (int dw=0; dw<3; dw++){
          #pragma unroll
          for (int o=0;o<COT;o++){
            float wv = s_w[o][c][dh*3+dw];
            acc[o][0][0] = fmaf(p[dh  ][dw  ], wv, acc[o][0][0]);
            acc[o][0][1] = fmaf(p[dh  ][dw+1], wv, acc[o][0][1]);
            acc[o][1][0] = fmaf(p[dh+1][dw  ], wv, acc[o][1][0]);
            acc[o][1][1] = fmaf(p[dh+1][dw+1], wv, acc[o][1][1]);
          }
        }
    }
    __syncthreads();
  }
  #pragma unroll
  for (int o=0;o<COT;o++){
    int co = co0 + o;
    if (co >= Cout) continue;
    float bv = bias[co];
    #pragma unroll
    for (int r=0;r<2;r++)
      #pragma unroll
      for (int s=0;s<2;s++){
        float v = acc[o][r][s] + bv;
        if (relu) v = fmaxf(v, 0.f);
        out[((size_t)(b*Cout + co)*H + h0+y0+r)*W + w0+x0+s] = v;
      }
  }
}

// ---- split-bf16 MFMA direct conv 3x3 SAME ----
// Requires Cin%32==0, Cout%64==0, H%8==0, W%8==0. Block: 64 Cout x 64 positions
// (8x8 pixel tile, halo 10x10). 4 waves of 32x32 (2x2 MFMA tiles each).
// Per Cin-chunk(32): 9 taps as 9 accumulation rounds; weights staged per-dh row.
__global__ __launch_bounds__(256) void convm(
    const float* __restrict__ in, const float* __restrict__ wgt,
    const float* __restrict__ bias, float* __restrict__ out,
    int Cin, int Cout, int H, int W, int relu)
{
  const int tilesW = W >> 3;
  const int h0 = (blockIdx.x / tilesW) << 3;
  const int w0 = (blockIdx.x % tilesW) << 3;
  const int co0 = blockIdx.y << 6;
  const int b  = blockIdx.z;
  const int tid = threadIdx.x;
  const int wid = tid >> 6, lane = tid & 63;
  const int wm = wid >> 1, wn = wid & 1;
  const int quad = lane >> 4, ln = lane & 15;

  // x tile: [px 0..99][ci 0..31] stride 40 (16B-aligned rows, 2-way banks = free)
  __shared__ __align__(16) u16 sXh[100*40], sXl[100*40];
  // w row tile: [dw 0..2][co 0..63][ci 0..31] stride 40
  __shared__ __align__(16) u16 sWh[3*64*40], sWl[3*64*40];

  f32x4 acc[2][2];
  #pragma unroll
  for (int i=0;i<2;i++)
    #pragma unroll
    for (int j=0;j<2;j++)
      #pragma unroll
      for (int e=0;e<4;e++) acc[i][j][e] = 0.f;

  for (int ci0 = 0; ci0 < Cin; ci0 += 32){
    __syncthreads();
    // stage x chunk (fp32 -> hi/lo bf16), 3200 elems
    for (int e = tid; e < 3200; e += 256){
      int ci = e / 100, px = e - ci*100;
      int pr = px / 10, pc = px - pr*10;
      int ih = h0 + pr - 1, iw = w0 + pc - 1;
      float v = 0.f;
      if ((unsigned)ih < (unsigned)H && (unsigned)iw < (unsigned)W)
        v = in[((size_t)(b*Cin + ci0+ci)*H + ih)*W + iw];
      u16 h = bf16_rne(v);
      sXh[px*40 + ci] = h;
      sXl[px*40 + ci] = bf16_rne(v - bf16f(h));
    }
    for (int dh = 0; dh < 3; ++dh){
      if (dh) __syncthreads();
      // stage weight row dh: 3 dw x 64 co x 32 ci = 6144 elems
      for (int e = tid; e < 6144; e += 256){
        int dw = e >> 11;
        int r  = e & 2047;
        int co = r >> 5, ci = r & 31;
        float v = wgt[((size_t)(co0+co)*Cin + ci0+ci)*9 + dh*3 + dw];
        u16 h = bf16_rne(v);
        sWh[(dw*64+co)*40 + ci] = h;
        sWl[(dw*64+co)*40 + ci] = bf16_rne(v - bf16f(h));
      }
      __syncthreads();
      #pragma unroll
      for (int dw = 0; dw < 3; ++dw){
        bf16x8 ah[2], al[2], bh[2], bl[2];
        #pragma unroll
        for (int t=0;t<2;t++){
          const int co_l = (wm*2+t)*16 + ln;
          const int wo = (dw*64 + co_l)*40 + quad*8;
          ah[t] = *(const bf16x8*)&sWh[wo];
          al[t] = *(const bf16x8*)&sWl[wo];
          const int p = (wn*2+t)*16 + ln;
          const int px = ((p>>3) + dh)*10 + (p&7) + dw;
          const int xo = px*40 + quad*8;
          bh[t] = *(const bf16x8*)&sXh[xo];
          bl[t] = *(const bf16x8*)&sXl[xo];
        }
        #pragma unroll
        for (int mi=0;mi<2;mi++)
          #pragma unroll
          for (int ni=0;ni<2;ni++){
            acc[mi][ni] = __builtin_amdgcn_mfma_f32_16x16x32_bf16(ah[mi], bh[ni], acc[mi][ni], 0, 0, 0);
            acc[mi][ni] = __builtin_amdgcn_mfma_f32_16x16x32_bf16(ah[mi], bl[ni], acc[mi][ni], 0, 0, 0);
            acc[mi][ni] = __builtin_amdgcn_mfma_f32_16x16x32_bf16(al[mi], bh[ni], acc[mi][ni], 0, 0, 0);
          }
      }
    }
  }
  // epilogue: C/D layout col=lane&15 (position), row=quad*4+reg (cout)
  #pragma unroll
  for (int mi=0;mi<2;mi++){
    const int co = co0 + (wm*2+mi)*16 + quad*4;
    #pragma unroll
    for (int ni=0;ni<2;ni++){
      const int p = (wn*2+ni)*16 + ln;
      const int oh = h0 + (p>>3), ow = w0 + (p&7);
      #pragma unroll
      for (int rg=0; rg<4; rg++){
        float v = acc[mi][ni][rg] + bias[co+rg];
        if (relu) v = fmaxf(v, 0.f);
        out[((size_t)(b*Cout + co+rg)*H + oh)*W + ow] = v;
      }
    }
  }
}

__global__ __launch_bounds__(256) void pool2k(const float* __restrict__ in, float* __restrict__ out,
                                              int n, int Ho, int Wo){
  int idx = blockIdx.x*256 + threadIdx.x;
  if (idx >= n) return;
  int wo = idx % Wo; int t = idx / Wo; int ho = t % Ho; int bc = t / Ho;
  const float* p = in + ((size_t)bc*(Ho*2) + ho*2)*(size_t)(Wo*2) + (size_t)wo*2;
  out[idx] = 0.25f*(p[0] + p[1] + p[2*Wo] + p[2*Wo+1]);
}

__global__ __launch_bounds__(256) void up2k(const float* __restrict__ in, float* __restrict__ out,
                                            int n, int Ho, int Wo){
  int idx = blockIdx.x*256 + threadIdx.x;
  if (idx >= n) return;
  int wo = idx % Wo; int t = idx / Wo; int ho = t % Ho; int bc = t / Ho;
  int Hi = Ho >> 1, Wi = Wo >> 1;
  out[idx] = in[((size_t)bc*Hi + (ho>>1))*Wi + (wo>>1)];
}

// per-(b,c) spatial mean & std (ddof=0)
__global__ __launch_bounds__(256) void statsk(const float* __restrict__ x, int HW,
                                              float* __restrict__ mo, float* __restrict__ so){
  int bc = blockIdx.x, tid = threadIdx.x;
  const float* p = x + (size_t)bc*HW;
  double s = 0.0, s2 = 0.0;
  for (int i = tid; i < HW; i += 256){ double v = p[i]; s += v; s2 += v*v; }
  __shared__ double sh[256], sh2[256];
  sh[tid] = s; sh2[tid] = s2; __syncthreads();
  for (int k=128;k>0;k>>=1){ if (tid<k){ sh[tid]+=sh[tid+k]; sh2[tid]+=sh2[tid+k]; } __syncthreads(); }
  if (tid == 0){
    double m = sh[0]/HW;
    double var = sh2[0]/HW - m*m;
    if (var < 0.0) var = 0.0;
    mo[bc] = (float)m;
    so[bc] = (float)sqrt(var);
  }
}

// f4 (C-major, per image 512x1024) -> ptsT [8][1024][512]
__global__ __launch_bounds__(256) void transposek(const float* __restrict__ f4c,
                                                  const float* __restrict__ f4s,
                                                  float* __restrict__ ptsT){
  __shared__ float t[32][33];
  int r = blockIdx.z;
  const float* src = (r < 4) ? (f4c + (size_t)r*524288) : (f4s + (size_t)(r-4)*524288);
  int n0 = blockIdx.x*32, c0 = blockIdx.y*32;
  int lx = threadIdx.x & 31, ly = threadIdx.x >> 5;
  for (int j=0;j<32;j+=8)
    t[ly+j][lx] = src[(size_t)(c0+ly+j)*1024 + n0+lx];
  __syncthreads();
  for (int j=0;j<32;j+=8)
    ptsT[((size_t)r*1024 + n0+ly+j)*512 + c0+lx] = t[lx][ly+j];
}

__global__ __launch_bounds__(256) void initcentk(const float* __restrict__ ptsT, float* __restrict__ cent){
  int i = blockIdx.x*256 + threadIdx.x;
  if (i >= 12288) return;
  int c = i & 511; int k = (i >> 9) % 3; int r = i / 1536;
  cent[i] = ptsT[((size_t)r*1024 + k)*512 + c];
}

// one wave per point; first-min argmin (matches jnp.argmin)
__global__ __launch_bounds__(256) void assignk(const float* __restrict__ ptsT,
                                               const float* __restrict__ cent, int* __restrict__ a){
  int gp = blockIdx.x*4 + (threadIdx.x >> 6);
  int lane = threadIdx.x & 63;
  int r = gp >> 10;
  const float* p = ptsT + (size_t)gp*512;
  const float* ce = cent + r*1536;
  float d0=0.f,d1=0.f,d2=0.f;
  #pragma unroll
  for (int i=0;i<8;i++){
    int c = lane + i*64;
    float v = p[c];
    float e0 = v - ce[c], e1 = v - ce[512+c], e2 = v - ce[1024+c];
    d0 = fmaf(e0,e0,d0); d1 = fmaf(e1,e1,d1); d2 = fmaf(e2,e2,d2);
  }
  #pragma unroll
  for (int off=32; off>0; off>>=1){
    d0 += __shfl_down(d0, off, 64);
    d1 += __shfl_down(d1, off, 64);
    d2 += __shfl_down(d2, off, 64);
  }
  if (lane == 0){
    int bi = 0; float bd = d0;
    if (d1 < bd){ bd = d1; bi = 1; }
    if (d2 < bd){ bd = d2; bi = 2; }
    a[gp] = bi;
  }
}

// parallel centroid update: grid (r=8, cc=16), 256 thr
template<int WRITE>
__global__ __launch_bounds__(256) void updatek(const float* __restrict__ ptsT,
                                               const int* __restrict__ a,
                                               float* __restrict__ dst,
                                               float* __restrict__ counts){
  int r = blockIdx.x, cc = blockIdx.y;
  int tid = threadIdx.x;
  int lane = tid & 31, p = tid >> 5;
  int c = cc*32 + lane;
  __shared__ int sa[1024];
  __shared__ int scnt[3];
  if (tid < 3) scnt[tid] = 0;
  for (int i = tid; i < 1024; i += 256) sa[i] = a[r*1024 + i];
  __syncthreads();
  {
    int l0=0,l1=0,l2=0;
    #pragma unroll
    for (int i=tid*4;i<tid*4+4;i++){ int an=sa[i]; l0+=(an==0); l1+=(an==1); l2+=(an==2); }
    if (l0) atomicAdd(&scnt[0], l0);
    if (l1) atomicAdd(&scnt[1], l1);
    if (l2) atomicAdd(&scnt[2], l2);
  }
  const float* base = ptsT + (size_t)r*524288;
  float s0=0.f,s1=0.f,s2=0.f;
  for (int n = p*128; n < p*128+128; ++n){
    float v = base[(size_t)n*512 + c];
    int an = sa[n];
    s0 += (an==0) ? v : 0.f;
    s1 += (an==1) ? v : 0.f;
    s2 += (an==2) ? v : 0.f;
  }
  __shared__ float red[8][3][32];
  red[p][0][lane]=s0; red[p][1][lane]=s1; red[p][2][lane]=s2;
  __syncthreads();
  if (p == 0){
    float t0=0.f,t1=0.f,t2=0.f;
    #pragma unroll
    for (int q=0;q<8;q++){ t0+=red[q][0][lane]; t1+=red[q][1][lane]; t2+=red[q][2][lane]; }
    float n0 = (float)scnt[0] + 1e-6f, n1 = (float)scnt[1] + 1e-6f, n2 = (float)scnt[2] + 1e-6f;
    if (WRITE == 0){
      dst[r*1536 + c]        = t0/n0;
      dst[r*1536 + 512 + c]  = t1/n1;
      dst[r*1536 + 1024 + c] = t2/n2;
    } else {
      int cs = r >> 2, img = r & 3;
      int i0 = cs*12 + img*3;
      dst[(size_t)(i0+0)*512 + c] = t0/n0;
      dst[(size_t)(i0+1)*512 + c] = t1/n1;
      dst[(size_t)(i0+2)*512 + c] = t2/n2;
      if (cc == 0 && lane == 0){
        counts[i0]   = (float)scnt[0];
        counts[i0+1] = (float)scnt[1];
        counts[i0+2] = (float)scnt[2];
      }
    }
  }
}

// 24 masked covariances: Y[z] = cov + 0.1 I   (z = cs*12 + img*3 + k)
__global__ __launch_bounds__(256) void covk(const float* __restrict__ f4c, const float* __restrict__ f4s,
        const int* __restrict__ a, const float* __restrict__ mu,
        const float* __restrict__ counts, float* __restrict__ Y){
  int z = blockIdx.z;
  int cs = z / 12; int rem = z - cs*12; int img = rem / 3; int k = rem - img*3;
  const float* pts = (cs ? f4s : f4c) + (size_t)img*524288;
  const int* an = a + (cs*4 + img)*1024;
  const float* m = mu + (size_t)z*512;
  float nc = counts[z] + 1e-6f;
  int I = blockIdx.y*64, J = blockIdx.x*64;
  __shared__ float SI[32][65], SJ[32][65];
  int tid = threadIdx.x;
  int tx = tid & 15, ty = tid >> 4;
  float acc[4][4] = {};
  for (int n0 = 0; n0 < 1024; n0 += 32){
    for (int e = tid; e < 2048; e += 256){
      int i = e >> 5, nn = e & 31;
      int n = n0 + nn;
      float msk = (an[n] == k) ? 1.f : 0.f;
      SI[nn][i] = msk * (pts[(size_t)(I+i)*1024 + n] - m[I+i]);
    }
    for (int e = tid; e < 2048; e += 256){
      int j = e >> 5, nn = e & 31;
      int n = n0 + nn;
      float msk = (an[n] == k) ? 1.f : 0.f;
      SJ[nn][j] = msk * (pts[(size_t)(J+j)*1024 + n] - m[J+j]);
    }
    __syncthreads();
    #pragma unroll 8
    for (int nn=0; nn<32; nn++){
      float ri[4], rj[4];
      #pragma unroll
      for (int q=0;q<4;q++){ ri[q] = SI[nn][ty*4+q]; rj[q] = SJ[nn][tx*4+q]; }
      #pragma unroll
      for (int qi=0;qi<4;qi++)
        #pragma unroll
        for (int qj=0;qj<4;qj++)
          acc[qi][qj] = fmaf(ri[qi], rj[qj], acc[qi][qj]);
    }
    __syncthreads();
  }
  float inv = 1.f/nc;
  #pragma unroll
  for (int qi=0;qi<4;qi++){
    int gi = I + ty*4 + qi;
    #pragma unroll
    for (int qj=0;qj<4;qj++){
      int gj = J + tx*4 + qj;
      Y[(size_t)z*MSZ + (size_t)gi*512 + gj] = acc[qi][qj]*inv + ((gi==gj)?0.1f:0.f);
    }
  }
}

// power iteration for lambda_max
__global__ __launch_bounds__(256) void powk(const float* __restrict__ Y, float* __restrict__ sval){
  int z = blockIdx.x, tid = threadIdx.x;
  const float* M = Y + (size_t)z*MSZ;
  __shared__ float v[512];
  __shared__ float red[256];
  __shared__ float nrmsh;
  v[tid] = 1.f; v[tid+256] = 1.f;
  __syncthreads();
  float lastn = 0.1f;
  for (int it=0; it<10; ++it){
    float y0=0.f, y1=0.f;
    for (int c=0;c<512;c++){
      float vc = v[c];
      y0 = fmaf(M[(size_t)c*512 + tid      ], vc, y0);
      y1 = fmaf(M[(size_t)c*512 + tid + 256], vc, y1);
    }
    red[tid] = y0*y0 + y1*y1;
    __syncthreads();
    for (int s=128;s>0;s>>=1){ if (tid<s) red[tid]+=red[tid+s]; __syncthreads(); }
    if (tid==0) nrmsh = sqrtf(red[0]) + 1e-30f;
    __syncthreads();
    float nrm = nrmsh;
    v[tid] = y0/nrm; v[tid+256] = y1/nrm;
    lastn = nrm;
    __syncthreads();
  }
  if (tid==0) sval[z] = lastn*1.05f + 1e-12f;
}

// init split planes: Y = Ycov/s (hi+lo bf16), Z = I
__global__ __launch_bounds__(256) void nsinitk(const float* __restrict__ Ycov, const float* __restrict__ sval,
                                               u16* __restrict__ Yh, u16* __restrict__ Yl,
                                               u16* __restrict__ Zh, u16* __restrict__ Zl){
  size_t idx = (size_t)blockIdx.x*256 + threadIdx.x;
  if (idx >= (size_t)PL) return;
  int z = (int)(idx >> 18);
  int rc = (int)(idx & (MSZ-1));
  int rr = rc >> 9, cc = rc & 511;
  float y = Ycov[idx] / sval[z];
  u16 h = bf16_rne(y);
  Yh[idx] = h;
  Yl[idx] = bf16_rne(y - bf16f(h));
  Zh[idx] = (rr==cc) ? (u16)0x3F80 : (u16)0;
  Zl[idx] = 0;
}

// trace-scaled NS factors from split M: g = min(512/tr, 2.7); os = sqrt(g)/2
__global__ __launch_bounds__(256) void scalek(const u16* __restrict__ Mh, const u16* __restrict__ Ml,
                                              float* __restrict__ g, float* __restrict__ os){
  int z = blockIdx.x, tid = threadIdx.x;
  const u16* H = Mh + (size_t)z*MSZ;
  const u16* L = Ml + (size_t)z*MSZ;
  float s = bf16f(H[(size_t)tid*513]) + bf16f(L[(size_t)tid*513])
          + bf16f(H[(size_t)(tid+256)*513]) + bf16f(L[(size_t)(tid+256)*513]);
  __shared__ float sh[256];
  sh[tid] = s; __syncthreads();
  for (int k=128;k>0;k>>=1){ if (tid<k) sh[tid]+=sh[tid+k]; __syncthreads(); }
  if (tid==0){
    float tr = fmaxf(sh[0], 1e-6f);
    float g2 = fminf(512.f/tr, 2.7f);
    g[z] = g2;
    os[z] = 0.5f*sqrtf(g2);
  }
}

// ---- split-bf16 MFMA batched GEMM, general B (staged transposed in LDS) ----
template<int MODE>
__global__ __launch_bounds__(256) void bmms(
    const u16* __restrict__ Ah, const u16* __restrict__ Al,
    const u16* __restrict__ Bh, const u16* __restrict__ Bl,
    const u16* __restrict__ Dh, const u16* __restrict__ Dl,
    u16* __restrict__ Ch, u16* __restrict__ Cl,
    float* __restrict__ Cf,
    const float* __restrict__ gam, const float* __restrict__ osc,
    int aoff)
{
  const int z = blockIdx.z;
  const u16* Abh = Ah + (size_t)(z+aoff)*MSZ;
  const u16* Abl = Al + (size_t)(z+aoff)*MSZ;
  const u16* Bbh = Bh + (size_t)z*MSZ;
  const u16* Bbl = Bl + (size_t)z*MSZ;
  const int m0 = blockIdx.y*128, n0 = blockIdx.x*128;
  const int tid = threadIdx.x;

  __shared__ __align__(16) u16 sAh[128*40], sAl[128*40];
  __shared__ __align__(16) u16 sBh[128*40], sBl[128*40];

  const int ra = tid >> 2, qa = tid & 3;
  const int kb = tid >> 4, gb = tid & 15;

  const int wid = tid >> 6, lane = tid & 63;
  const int wm = wid >> 1, wn = wid & 1;
  const int quad = lane >> 4, ln = lane & 15;

  f32x4 acc[4][4];
  #pragma unroll
  for (int i=0;i<4;i++)
    #pragma unroll
    for (int j=0;j<4;j++)
      #pragma unroll
      for (int e=0;e<4;e++) acc[i][j][e] = 0.f;

  for (int k0 = 0; k0 < 512; k0 += 32){
    *(bf16x8*)&sAh[ra*40 + qa*8]      = *(const bf16x8*)&Abh[(size_t)(m0+ra)*512    + k0 + qa*8];
    *(bf16x8*)&sAl[ra*40 + qa*8]      = *(const bf16x8*)&Abl[(size_t)(m0+ra)*512    + k0 + qa*8];
    *(bf16x8*)&sAh[(ra+64)*40 + qa*8] = *(const bf16x8*)&Abh[(size_t)(m0+ra+64)*512 + k0 + qa*8];
    *(bf16x8*)&sAl[(ra+64)*40 + qa*8] = *(const bf16x8*)&Abl[(size_t)(m0+ra+64)*512 + k0 + qa*8];
    {
      bf16x8 vh = *(const bf16x8*)&Bbh[(size_t)(k0+kb)*512 + n0 + gb*8];
      bf16x8 vl = *(const bf16x8*)&Bbl[(size_t)(k0+kb)*512 + n0 + gb*8];
      #pragma unroll
      for (int j=0;j<8;j++){
        sBh[(gb*8+j)*40 + kb] = (u16)vh[j];
        sBl[(gb*8+j)*40 + kb] = (u16)vl[j];
      }
      vh = *(const bf16x8*)&Bbh[(size_t)(k0+kb+16)*512 + n0 + gb*8];
      vl = *(const bf16x8*)&Bbl[(size_t)(k0+kb+16)*512 + n0 + gb*8];
      #pragma unroll
      for (int j=0;j<8;j++){
        sBh[(gb*8+j)*40 + kb+16] = (u16)vh[j];
        sBl[(gb*8+j)*40 + kb+16] = (u16)vl[j];
      }
    }
    __syncthreads();

    bf16x8 ah[4], al[4], bh[4], bl[4];
    #pragma unroll
    for (int t=0;t<4;t++){
      const int moA = ((wm*4+t)*16 + ln)*40 + quad*8;
      const int moB = ((wn*4+t)*16 + ln)*40 + quad*8;
      ah[t] = *(const bf16x8*)&sAh[moA];
      al[t] = *(const bf16x8*)&sAl[moA];
      bh[t] = *(const bf16x8*)&sBh[moB];
      bl[t] = *(const bf16x8*)&sBl[moB];
    }
    #pragma unroll
    for (int mi=0;mi<4;mi++)
      #pragma unroll
      for (int ni=0;ni<4;ni++){
        acc[mi][ni] = __builtin_amdgcn_mfma_f32_16x16x32_bf16(ah[mi], bh[ni], acc[mi][ni], 0, 0, 0);
        acc[mi][ni] = __builtin_amdgcn_mfma_f32_16x16x32_bf16(ah[mi], bl[ni], acc[mi][ni], 0, 0, 0);
        acc[mi][ni] = __builtin_amdgcn_mfma_f32_16x16x32_bf16(al[mi], bh[ni], acc[mi][ni], 0, 0, 0);
      }
    __syncthreads();
  }

  float alpha = 1.f, beta = 0.f;
  if constexpr (MODE==1){ float gz = gam[z], oz = osc[z]; alpha = -gz*oz; beta = 3.f*oz; }
  if constexpr (MODE==2){ alpha = osc[z]; }

  #pragma unroll
  for (int mi=0;mi<4;mi++){
    const int mbase = m0 + (wm*4+mi)*16 + quad*4;
    #pragma unroll
    for (int ni=0;ni<4;ni++){
      const int n = n0 + (wn*4+ni)*16 + ln;
      #pragma unroll
      for (int rg=0;rg<4;rg++){
        const int m = mbase + rg;
        const size_t off = (size_t)z*MSZ + (size_t)m*512 + n;
        float v = alpha*acc[mi][ni][rg];
        if constexpr (MODE==1)
          v += beta*(bf16f(Dh[off]) + bf16f(Dl[off]));
        if constexpr (MODE==2){
          Cf[off] = v;
        } else {
          u16 h = bf16_rne(v);
          Ch[off] = h;
          Cl[off] = bf16_rne(v - bf16f(h));
        }
      }
    }
  }
}

// batched fp32 GEMM (kept for tpts = T @ f, non-symmetric operands)
template<int TRANS>
__global__ __launch_bounds__(256) void bmmk(const float* __restrict__ A, const float* __restrict__ B,
        float* __restrict__ C, int M, int N, int K,
        long long sA, long long sB, long long sC, int bdiv,
        const float* __restrict__ gam, const float* __restrict__ osc)
{
  int bz = blockIdx.z;
  const float* Ab = A + (size_t)bz*sA;
  const float* Bb = B + (size_t)(bz/bdiv)*sB;
  float* Cb = C + (size_t)bz*sC;
  const float g = (TRANS != 0 && gam) ? gam[bz] : 1.0f;
  const int m0 = blockIdx.y << 7, n0 = blockIdx.x << 6;
  const int tid = threadIdx.x;
  const int trow = tid >> 4;
  const int tcol = tid & 15;
  __shared__ __align__(16) float As[16][132];
  __shared__ __align__(16) float Bs[16][68];
  float acc[8][4] = {};
  for (int k0 = 0; k0 < K; k0 += 16){
    #pragma unroll
    for (int l=0;l<2;l++){
      int e = tid + l*256;
      int m = e >> 2;
      int kq = (e & 3) << 2;
      float4 v4 = *(const float4*)(Ab + (size_t)(m0+m)*K + k0 + kq);
      float vv[4] = {v4.x, v4.y, v4.z, v4.w};
      #pragma unroll
      for (int j=0;j<4;j++){
        float v = vv[j];
        if (TRANS==1) v = 3.0f*(((k0+kq+j)==(m0+m)) ? 1.f : 0.f) - g*v;
        As[kq+j][m] = v;
      }
    }
    {
      int kk = tid >> 4;
      int nq = (tid & 15) << 2;
      float4 v4 = *(const float4*)(Bb + (size_t)(k0+kk)*N + n0 + nq);
      float vv[4] = {v4.x, v4.y, v4.z, v4.w};
      #pragma unroll
      for (int j=0;j<4;j++){
        if (TRANS==2) vv[j] = 3.0f*(((k0+kk)==(n0+nq+j)) ? 1.f : 0.f) - g*vv[j];
      }
      *(float4*)(&Bs[kk][nq]) = make_float4(vv[0],vv[1],vv[2],vv[3]);
    }
    __syncthreads();
    #pragma unroll
    for (int kk=0;kk<16;kk++){
      float a8[8];
      *(float4*)(a8)     = *(const float4*)(&As[kk][trow*8]);
      *(float4*)(a8 + 4) = *(const float4*)(&As[kk][trow*8 + 4]);
      float4 b4 = *(const float4*)(&Bs[kk][tcol*4]);
      float bb[4] = {b4.x, b4.y, b4.z, b4.w};
      #pragma unroll
      for (int i=0;i<8;i++)
        #pragma unroll
        for (int j=0;j<4;j++)
          acc[i][j] = fmaf(a8[i], bb[j], acc[i][j]);
    }
    __syncthreads();
  }
  const float sc = osc ? osc[bz] : 1.0f;
  #pragma unroll
  for (int i=0;i<8;i++){
    int m = m0 + trow*8 + i;
    float4 o = make_float4(acc[i][0]*sc, acc[i][1]*sc, acc[i][2]*sc, acc[i][3]*sc);
    *(float4*)(Cb + (size_t)m*N + n0 + tcol*4) = o;
  }
}

__global__ void make_scalesk(const float* __restrict__ sval, float* __restrict__ scl){
  int i = threadIdx.x;
  if (i < 12) scl[i] = sqrtf(sval[12+i] / sval[i]);
}

// tvec[b] = mu_s[b] - T[b] @ mu_c[b]
__global__ __launch_bounds__(512) void tveck(const float* __restrict__ Tmat,
                                             const float* __restrict__ mu, float* __restrict__ tvec){
  int b = blockIdx.x; int c = threadIdx.x;
  __shared__ float mc[512];
  mc[c] = mu[(size_t)b*512 + c];
  __syncthreads();
  const float* Trow = Tmat + ((size_t)b*512 + c)*512;
  float s = 0.f;
  for (int d=0; d<512; d++) s = fmaf(Trow[d], mc[d], s);
  tvec[b*512 + c] = mu[(size_t)(12+b)*512 + c] - s;
}

__global__ __launch_bounds__(256) void selectk(const float* __restrict__ tpts, const float* __restrict__ tvec,
        const int* __restrict__ a, const float* __restrict__ f4c, float* __restrict__ tf){
  size_t idx = (size_t)blockIdx.x*256 + threadIdx.x;
  if (idx >= 2097152ul) return;
  int n = (int)(idx & 1023);
  int c = (int)((idx >> 10) & 511);
  int img = (int)(idx >> 19);
  int k = a[img*1024 + n];
  int b = img*3 + k;
  float v = tpts[((size_t)b*512 + c)*1024 + n] + tvec[b*512 + c];
  tf[idx] = 0.6f*v + 0.4f*f4c[idx];
}

__global__ __launch_bounds__(256) void clossk(const float* __restrict__ x, const float* __restrict__ y,
                                              int n, float* __restrict__ acc){
  int tid = threadIdx.x;
  float s = 0.f;
  for (size_t i = (size_t)blockIdx.x*256 + tid; i < (size_t)n; i += (size_t)gridDim.x*256){
    float d = x[i] - y[i]; s = fmaf(d, d, s);
  }
  __shared__ float sh[256];
  sh[tid] = s; __syncthreads();
  for (int k=128;k>0;k>>=1){ if (tid<k) sh[tid]+=sh[tid+k]; __syncthreads(); }
  if (tid==0) atomicAdd(acc, sh[0]);
}

__global__ __launch_bounds__(256) void finalk(const float* __restrict__ sm, float* __restrict__ out){
  int tid = threadIdx.x;
  const int cnts[4] = {256,512,1024,2048};
  const int offs[4] = {0,256,768,1792};
  const float* mS = sm + SM_STATS_S;
  const float* sS = sm + SM_STATS_S + 3840;
  const float* mD = sm + SM_STATS_D;
  const float* sD = sm + SM_STATS_D + 3840;
  double sl = 0.0;
  for (int L=0; L<4; ++L){
    int cnt = cnts[L], off = offs[L];
    double inv = 1.0/cnt;
    for (int i=tid; i<cnt; i+=256){
      double dm = (double)mD[off+i] - (double)mS[off+i];
      double ds = (double)sD[off+i] - (double)sS[off+i];
      sl += (dm*dm + ds*ds)*inv;
    }
  }
  __shared__ double sh[256];
  sh[tid] = sl; __syncthreads();
  for (int k=128;k>0;k>>=1){ if (tid<k) sh[tid]+=sh[tid+k]; __syncthreads(); }
  if (tid==0){
    double closs = (double)sm[SM_CLOSS] / 2097152.0;
    out[0] = (float)(closs + 0.01*sh[0]);
  }
}

// ---------------- host ----------------

extern "C" void kernel_launch(void* const* d_in, const int* in_sizes, int n_in,
                              void* d_out, int out_size, void* d_ws, size_t ws_size,
                              hipStream_t stream)
{
  const float* content = (const float*)d_in[0];
  const float* style   = (const float*)d_in[1];
  const float* Wm[8]; const float* Bm[8];
  for (int i=0;i<8;i++){ Wm[i] = (const float*)d_in[2+2*i]; Bm[i] = (const float*)d_in[3+2*i]; }
  float* out = (float*)d_out;
  float* ws = (float*)d_ws;

  float* f4c  = ws + OFF_F4C;
  float* f4s  = ws + OFF_F4S;
  float* tf   = ws + OFF_TF;
  float* dec  = ws + OFF_DEC;
  float* Tmat = ws + OFF_TMAT;
  float* sm   = ws + OFF_SMALL;
  float* AR   = ws + OFF_ARENA;
  int*   aPtr = (int*)(sm + SM_ASSIGN);
  float* cent = sm + SM_CENT;
  float* mu   = sm + SM_MU;
  float* counts = sm + SM_COUNTS;
  float* sval = sm + SM_SVAL;
  float* scl  = sm + SM_SCALE;
  float* tvec = sm + SM_TVEC;
  float* gbuf = sm + SM_G;
  float* obuf = sm + SM_OS;

  // NS split planes (u16), each 24*MSZ elements = 3145728 float-slots
  float* Ycov = AR;                       // fp32, dead after nsinitk
  u16* Mh  = (u16*)(AR);                  // reuses Ycov region
  u16* Ml  = (u16*)(AR + 3145728ul);
  u16* Yh  = (u16*)(AR + 6291456ul);
  u16* Yl  = (u16*)(AR + 9437184ul);
  u16* Zh  = (u16*)(AR + 12582912ul);
  u16* Zl  = (u16*)(AR + 15728640ul);
  u16* Y2h = (u16*)(AR + 18874368ul);
  u16* Y2l = (u16*)(AR + 22020096ul);
  u16* Z2h = (u16*)(AR + 25165824ul);
  u16* Z2l = (u16*)(AR + 28311552ul);
  float* ptsT = AR + 25165824ul;   // dead before Z2 planes are first written

  zerok<<<512,256,0,stream>>>(sm, 131072);

  auto conv = [&](const float* inp, int li, float* outp, int Ci,int Co,int H,int Wd,int relu,int cot){
    dim3 g((H>>5)*(Wd>>5), (Co + cot - 1)/cot, 4);
    if (cot==8) conv3x3<8><<<g,256,0,stream>>>(inp,Wm[li],Bm[li],outp,4,Ci,Co,H,Wd,relu);
    else        conv3x3<4><<<g,256,0,stream>>>(inp,Wm[li],Bm[li],outp,4,Ci,Co,H,Wd,relu);
  };
  auto convM = [&](const float* inp, int li, float* outp, int Ci,int Co,int H,int Wd,int relu){
    dim3 g((H>>3)*(Wd>>3), Co>>6, 4);
    convm<<<g,256,0,stream>>>(inp,Wm[li],Bm[li],outp,Ci,Co,H,Wd,relu);
  };
  auto pool = [&](const float* inp, float* outp, int C,int Ho,int Wo){
    int n = 4*C*Ho*Wo;
    pool2k<<<(n+255)/256,256,0,stream>>>(inp,outp,n,Ho,Wo);
  };
  auto up = [&](const float* inp, float* outp, int C,int Ho,int Wo){
    int n = 4*C*Ho*Wo;
    up2k<<<(n+255)/256,256,0,stream>>>(inp,outp,n,Ho,Wo);
  };

  // encode scratch (arena)
  float* F1 = AR + 0;
  float* P1 = AR + 16777216ul;
  float* F2 = AR + 0;
  float* P2 = AR + 8388608ul;
  float* F3 = AR + 10485760ul;
  float* P3 = AR + 0;

  // ---- content encode ----
  conv(content, 0, F1, 3,64,256,256,1,8);
  pool(F1,P1,64,128,128);
  convM(P1,1,F2, 64,128,128,128,1);
  pool(F2,P2,128,64,64);
  convM(P2,2,F3, 128,256,64,64,1);
  pool(F3,P3,256,32,32);
  convM(P3,3,f4c, 256,512,32,32,1);

  // ---- style encode + stats ----
  float* mS = sm + SM_STATS_S;
  float* sS = sm + SM_STATS_S + 3840;
  conv(style, 0, F1, 3,64,256,256,1,8);
  statsk<<<256,256,0,stream>>>(F1,65536, mS+0, sS+0);
  pool(F1,P1,64,128,128);
  convM(P1,1,F2, 64,128,128,128,1);
  statsk<<<512,256,0,stream>>>(F2,16384, mS+256, sS+256);
  pool(F2,P2,128,64,64);
  convM(P2,2,F3, 128,256,64,64,1);
  statsk<<<1024,256,0,stream>>>(F3,4096, mS+768, sS+768);
  pool(F3,P3,256,32,32);
  convM(P3,3,f4s, 256,512,32,32,1);
  statsk<<<2048,256,0,stream>>>(f4s,1024, mS+1792, sS+1792);

  // ---- k-means (content r=0..3, style r=4..7) ----
  transposek<<<dim3(32,16,8),256,0,stream>>>(f4c,f4s,ptsT);
  initcentk<<<48,256,0,stream>>>(ptsT,cent);
  for (int it=0; it<10; ++it){
    assignk<<<2048,256,0,stream>>>(ptsT,cent,aPtr);
    updatek<0><<<dim3(8,16),256,0,stream>>>(ptsT,aPtr,cent,nullptr);
  }
  assignk<<<2048,256,0,stream>>>(ptsT,cent,aPtr);
  updatek<1><<<dim3(8,16),256,0,stream>>>(ptsT,aPtr,mu,counts);

  // ---- covariances + split-bf16 MFMA Newton-Schulz ----
  covk<<<dim3(8,8,24),256,0,stream>>>(f4c,f4s,aPtr,mu,counts,Ycov);
  powk<<<24,256,0,stream>>>(Ycov,sval);
  nsinitk<<<24576,256,0,stream>>>(Ycov,sval,Yh,Yl,Zh,Zl);
  u16 *Ych=Yh,*Ycl=Yl,*Zch=Zh,*Zcl=Zl,*Yah=Y2h,*Yal=Y2l,*Zah=Z2h,*Zal=Z2l;
  for (int it=0; it<NS_ITERS; ++it){
    bmms<0><<<dim3(4,4,24),256,0,stream>>>(Zch,Zcl,Ych,Ycl,nullptr,nullptr,Mh,Ml,nullptr,nullptr,nullptr,0);
    scalek<<<24,256,0,stream>>>(Mh,Ml,gbuf,obuf);
    bmms<1><<<dim3(4,4,24),256,0,stream>>>(Ych,Ycl,Mh,Ml,Ych,Ycl,Yah,Yal,nullptr,gbuf,obuf,0);
    bmms<1><<<dim3(4,4,24),256,0,stream>>>(Mh,Ml,Zch,Zcl,Zch,Zcl,Zah,Zal,nullptr,gbuf,obuf,0);
    u16* t;
    t=Ych;Ych=Yah;Yah=t; t=Ycl;Ycl=Yal;Yal=t;
    t=Zch;Zch=Zah;Zah=t; t=Zcl;Zcl=Zal;Zal=t;
  }
  // T[b] = sqrt(s_s/s_c) * Y_style[b] @ Z_content[b]  (fp32 out)
  make_scalesk<<<1,64,0,stream>>>(sval,scl);
  bmms<2><<<dim3(4,4,12),256,0,stream>>>(Ych,Ycl,Zch,Zcl,nullptr,nullptr,nullptr,nullptr,Tmat,nullptr,scl,12);
  tveck<<<12,512,0,stream>>>(Tmat,mu,tvec);
  // tpts[b] = T[b] @ f[img]   (b = img*3+k), fp32
  float* Mb = AR + 0;
  bmmk<0><<<dim3(16,4,12),256,0,stream>>>(Tmat, f4c, Mb, 512,1024,512,
                                          (long long)MSZ,524288ll,524288ll,3,nullptr,nullptr);
  selectk<<<8192,256,0,stream>>>(Mb,tvec,aPtr,f4c,tf);

  // ---- decode ----
  float* X1 = AR + 0;
  float* U1 = AR + 1048576ul;
  float* X2 = AR + 5242880ul;
  float* U2 = AR + 7340032ul;
  float* X3 = AR + 0;
  float* U3 = AR + 4194304ul;
  convM(tf, 4, X1, 512,256,32,32,1);
  up(X1,U1,256,64,64);
  convM(U1,5,X2, 256,128,64,64,1);
  up(X2,U2,128,128,128);
  convM(U2,6,X3, 128,64,128,128,1);
  up(X3,U3,64,256,256);
  conv(U3,7,dec, 64,3,256,256,0,4);

  // ---- decoded encode + stats + content loss ----
  float* mD = sm + SM_STATS_D;
  float* sD = sm + SM_STATS_D + 3840;
  conv(dec, 0, F1, 3,64,256,256,1,8);
  statsk<<<256,256,0,stream>>>(F1,65536, mD+0, sD+0);
  pool(F1,P1,64,128,128);
  convM(P1,1,F2, 64,128,128,128,1);
  statsk<<<512,256,0,stream>>>(F2,16384, mD+256, sD+256);
  pool(F2,P2,128,64,64);
  convM(P2,2,F3, 128,256,64,64,1);
  statsk<<<1024,256,0,stream>>>(F3,4096, mD+768, sD+768);
  pool(F3,P3,256,32,32);
  convM(P3,3,tf, 256,512,32,32,1);   // f4(dec) reuses tf buffer
  statsk<<<2048,256,0,stream>>>(tf,1024, mD+1792, sD+1792);
  clossk<<<2048,256,0,stream>>>(tf,f4c,2097152, sm+SM_CLOSS);
  finalk<<<1,256,0,stream>>>(sm,out);
}